// Round 6
// baseline (386.714 us; speedup 1.0000x reference)
//
#include <hip/hip_runtime.h>
#include <math.h>

#define NN 50000

typedef __attribute__((ext_vector_type(8))) short bf16x8;
typedef __attribute__((ext_vector_type(4))) float f32x4;

__device__ inline float wred_max(float v){
  #pragma unroll
  for(int s=32;s>0;s>>=1) v=fmaxf(v,__shfl_xor(v,s,64));
  return v;
}
__device__ inline float wred_sum(float v){
  #pragma unroll
  for(int s=32;s>0;s>>=1) v+=__shfl_xor(v,s,64);
  return v;
}
__device__ inline float lrelu(float x){ return x>0.f? x : 0.2f*x; }
__device__ inline float rlf(float v,int l){ return __int_as_float(__builtin_amdgcn_readlane(__float_as_int(v),l)); }

__device__ inline ushort f2bf(float f){
  union{float f;unsigned u;} v; v.f=f;
  unsigned u=v.u;
  return (ushort)((u + 0x7fffu + ((u>>16)&1u)) >> 16);
}
__device__ inline float bflo(unsigned u){ return __uint_as_float(u<<16); }
__device__ inline float bfhi(unsigned u){ return __uint_as_float(u&0xffff0000u); }

// ---------------- casts (weights only) ----------------
__global__ void casttr_k(const float* __restrict__ W, ushort* __restrict__ Wt, int K, int N){
  int i=blockIdx.x*blockDim.x+threadIdx.x;
  if(i<K*N){ int k=i/N, n=i%N; Wt[n*K+k]=f2bf(W[i]); }
}

// ---------------- CSR build ----------------
__global__ void hist_k(const int* __restrict__ dstA,int* __restrict__ counts,int E){
  int i=blockIdx.x*blockDim.x+threadIdx.x;
  if(i<E) atomicAdd(&counts[dstA[i]],1);
}

__global__ __launch_bounds__(1024) void scan1_k(const int* __restrict__ counts,int* __restrict__ offs,
                                                int* __restrict__ bsum,int N){
  __shared__ int stot[16];
  int t=threadIdx.x; int lane=t&63, wv=t>>6;
  int base=blockIdx.x*1024;
  int orig=(base+t<N)?counts[base+t]:0;
  int v=orig;
  #pragma unroll
  for(int s=1;s<64;s<<=1){ int u=__shfl_up(v,s,64); if(lane>=s) v+=u; }
  if(lane==63) stot[wv]=v;
  __syncthreads();
  if(wv==0){
    int tv=(lane<16)?stot[lane]:0;
    #pragma unroll
    for(int s=1;s<16;s<<=1){ int u=__shfl_up(tv,s,64); if(lane>=s) tv+=u; }
    if(lane<16) stot[lane]=tv;
  }
  __syncthreads();
  int wpref=(wv>0)?stot[wv-1]:0;
  if(base+t<N) offs[base+t]=wpref+v-orig;
  if(t==1023) bsum[blockIdx.x]=stot[15];
}
__global__ void scan2_k(int* __restrict__ bsum,int NB){
  int lane=threadIdx.x;
  int v=(lane<NB)?bsum[lane]:0;
  int incl=v;
  #pragma unroll
  for(int s=1;s<64;s<<=1){ int u=__shfl_up(incl,s,64); if(lane>=s) incl+=u; }
  if(lane<NB) bsum[lane]=incl-v;
}
__global__ __launch_bounds__(1024) void scan3_k(int* __restrict__ offs,const int* __restrict__ bsum,int N,int E){
  int i=blockIdx.x*1024+threadIdx.x;
  if(i<N) offs[i]+=bsum[blockIdx.x];
  if(i==N-1) offs[N]=E;
}

__global__ void scatter_k(const int* __restrict__ srcA,const int* __restrict__ dstA,
                          const int* __restrict__ offs,int* cur,int* __restrict__ ssrc,int E){
  int i=blockIdx.x*blockDim.x+threadIdx.x;
  if(i<E){ int d=dstA[i]; int p=offs[d]+atomicAdd(&cur[d],1); ssrc[p]=srcA[i]; }
}

// ---------------- bf16 MFMA GEMM + fused attention dots ----------------
// C = A[M,K] @ Bt[N,K]^T, tile BM x BN, grid (N/BN, M/BM).
// DOTM=1: heads=4, N=256, BN=128 (block covers heads bx*2,bx*2+1; each wave's
//         64 cols = one head). Store bf16 head-interleaved perm: chan gc -> 4*(gc&63)+(gc>>6).
//         Dots -> as_[gr*4+h], ad_[gr*4+h].
// DOTM=2: heads=1, N=32, single block-x. Store bf16 row-major; dots -> as_[gr], ad_[gr].
template<int WR,int WC,int MI,int NI,int DOTM,int AF32>
__global__ __launch_bounds__(256,2) void gemm_bf16_k(const void* __restrict__ Av,
    const ushort* __restrict__ Bt, ushort* __restrict__ C,
    const float* __restrict__ aS, const float* __restrict__ aD,
    float* __restrict__ as_, float* __restrict__ ad_,
    int M, int N, int K){
  constexpr int BM = WR*MI*16;
  constexpr int BN = WC*NI*16;
  constexpr int LDK = 40;
  __shared__ ushort sA[BM*LDK];
  __shared__ ushort sB[BN*LDK];
  int tid=threadIdx.x;
  int lane=tid&63, w=tid>>6;
  int wr=w/WC, wc=w%WC;
  int bm=blockIdx.y*BM, bn=blockIdx.x*BN;
  f32x4 acc[MI][NI]={};

  for(int k0=0;k0<K;k0+=32){
    if constexpr (AF32){
      const float* A=(const float*)Av;
      #pragma unroll
      for(int i=0;i<(BM*8)/256;i++){
        int c=tid+i*256;
        int r=c>>3, cc=c&7;
        int gr=bm+r;
        float4 v={0.f,0.f,0.f,0.f};
        if(gr<M) v=*(const float4*)(A+(size_t)gr*K+k0+cc*4);
        unsigned long long p=(unsigned long long)f2bf(v.x)
          |((unsigned long long)f2bf(v.y)<<16)
          |((unsigned long long)f2bf(v.z)<<32)
          |((unsigned long long)f2bf(v.w)<<48);
        *(unsigned long long*)(sA+r*LDK+cc*4)=p;
      }
    } else {
      const ushort* A=(const ushort*)Av;
      #pragma unroll
      for(int i=0;i<(BM*4)/256;i++){
        int c=tid+i*256;
        int r=c>>2, cc=c&3;
        int gr=bm+r;
        ulonglong2 v; v.x=0; v.y=0;
        if(gr<M) v=*(const ulonglong2*)(A+(size_t)gr*K+k0+cc*8);
        *(ulonglong2*)(sA+r*LDK+cc*8)=v;
      }
    }
    if constexpr ((BN*4)>=256){
      #pragma unroll
      for(int i=0;i<(BN*4)/256;i++){
        int c=tid+i*256;
        int r=c>>2, cc=c&3;
        ulonglong2 v=*(const ulonglong2*)(Bt+(size_t)(bn+r)*K+k0+cc*8);
        *(ulonglong2*)(sB+r*LDK+cc*8)=v;
      }
    } else {
      if(tid<BN*4){
        int r=tid>>2, cc=tid&3;
        ulonglong2 v=*(const ulonglong2*)(Bt+(size_t)(bn+r)*K+k0+cc*8);
        *(ulonglong2*)(sB+r*LDK+cc*8)=v;
      }
    }
    __syncthreads();
    bf16x8 af[MI], bf[NI];
    #pragma unroll
    for(int m=0;m<MI;m++)
      af[m]=*(bf16x8*)(sA+((wr*MI+m)*16+(lane&15))*LDK+(lane>>4)*8);
    #pragma unroll
    for(int n=0;n<NI;n++)
      bf[n]=*(bf16x8*)(sB+((wc*NI+n)*16+(lane&15))*LDK+(lane>>4)*8);
    #pragma unroll
    for(int m=0;m<MI;m++)
      #pragma unroll
      for(int n=0;n<NI;n++)
        acc[m][n]=__builtin_amdgcn_mfma_f32_16x16x32_bf16(af[m],bf[n],acc[m][n],0,0,0);
    __syncthreads();
  }
  int rb=lane>>4, cl=lane&15;
  float av[NI], dv[NI];
  #pragma unroll
  for(int n=0;n<NI;n++){
    int gc=bn+(wc*NI+n)*16+cl;
    if constexpr (DOTM!=0){ av[n]=aS[gc]; dv[n]=aD[gc]; }
    else { av[n]=0.f; dv[n]=0.f; }
  }
  #pragma unroll
  for(int m=0;m<MI;m++){
    #pragma unroll
    for(int i=0;i<4;i++){
      int gr=bm+(wr*MI+m)*16+rb*4+i;
      if constexpr (DOTM==1){
        // this wave's NI=4 cols all belong to head h
        int h=(bn>>6)+wc;
        float ps=0.f,pd=0.f;
        #pragma unroll
        for(int n=0;n<NI;n++){ ps+=acc[m][n][i]*av[n]; pd+=acc[m][n][i]*dv[n]; }
        #pragma unroll
        for(int msk=1;msk<16;msk<<=1){
          ps+=__shfl_xor(ps,msk,64); pd+=__shfl_xor(pd,msk,64);
        }
        if(cl==0 && gr<M){ as_[gr*4+h]=ps; ad_[gr*4+h]=pd; }
      } else if constexpr (DOTM==2){
        float ps=0.f,pd=0.f;
        #pragma unroll
        for(int n=0;n<NI;n++){ ps+=acc[m][n][i]*av[n]; pd+=acc[m][n][i]*dv[n]; }
        #pragma unroll
        for(int msk=1;msk<16;msk<<=1){
          ps+=__shfl_xor(ps,msk,64); pd+=__shfl_xor(pd,msk,64);
        }
        if(cl==0 && gr<M){ as_[gr]=ps; ad_[gr]=pd; }
      }
      if(gr<M){
        #pragma unroll
        for(int n=0;n<NI;n++){
          int gc=bn+(wc*NI+n)*16+cl;
          int pos = (DOTM==1) ? (4*(gc&63)+(gc>>6)) : gc;
          C[(size_t)gr*N+pos]=f2bf(acc[m][n][i]);
        }
      }
    }
  }
}

// ---------------- aggregation (heads=4, bf16 permuted h) + bias + LN + ELU ----------------
__global__ __launch_bounds__(256,4) void agg4_k(const ushort* __restrict__ hb,
    const float* __restrict__ as_,const float* __restrict__ ad_,
    const int* __restrict__ offs,const int* __restrict__ ssrc,
    const float* __restrict__ bias,const float* __restrict__ g,const float* __restrict__ be,
    ushort* __restrict__ outb,int N){
  int lane=threadIdx.x&63, wv=threadIdx.x>>6;
  int n=blockIdx.x*4+wv; if(n>=N) return;
  int lane4=lane*4;
  float ad[4], es[4];
  #pragma unroll
  for(int k=0;k<4;k++) ad[k]=ad_[n*4+k];
  #pragma unroll
  for(int k=0;k<4;k++) es[k]=lrelu(as_[n*4+k]+ad[k]);
  int o0=offs[n],o1=offs[n+1];
  int cnt=o1-o0;
  float m[4], inv[4], acc[4];

  if(cnt<=64){
    // ---- fast path: single gather, logits in registers, deep-pipelined accumulate ----
    int sv=0;
    float lv[4]={-1e30f,-1e30f,-1e30f,-1e30f};
    if(lane<cnt){
      sv=ssrc[o0+lane];
      float4 avv=*(const float4*)(as_+(size_t)sv*4);
      lv[0]=lrelu(avv.x+ad[0]); lv[1]=lrelu(avv.y+ad[1]);
      lv[2]=lrelu(avv.z+ad[2]); lv[3]=lrelu(avv.w+ad[3]);
    }
    #pragma unroll
    for(int k=0;k<4;k++) m[k]=fmaxf(es[k],wred_max(lv[k]));
    float w4[4];
    #pragma unroll
    for(int k=0;k<4;k++) w4[k]=(lane<cnt)?__expf(lv[k]-m[k]):0.f;
    #pragma unroll
    for(int k=0;k<4;k++){
      float z=wred_sum(w4[k])+__expf(es[k]-m[k]);
      inv[k]=1.f/(z+1e-16f);
    }
    #pragma unroll
    for(int k=0;k<4;k++) w4[k]*=inv[k];
    {
      uint2 u=*(const uint2*)(hb+(size_t)n*256+lane4);
      float hv[4]={bflo(u.x),bfhi(u.x),bflo(u.y),bfhi(u.y)};
      #pragma unroll
      for(int k=0;k<4;k++) acc[k]=__expf(es[k]-m[k])*inv[k]*hv[k];
    }
    int t=0;
    for(; t+16<=cnt; t+=16){
      uint2 u[16];
      #pragma unroll
      for(int i=0;i<16;i++){
        int s=__builtin_amdgcn_readlane(sv,t+i);
        u[i]=*(const uint2*)(hb+(size_t)s*256+lane4);
      }
      #pragma unroll
      for(int i=0;i<16;i++){
        acc[0]+=rlf(w4[0],t+i)*bflo(u[i].x);
        acc[1]+=rlf(w4[1],t+i)*bfhi(u[i].x);
        acc[2]+=rlf(w4[2],t+i)*bflo(u[i].y);
        acc[3]+=rlf(w4[3],t+i)*bfhi(u[i].y);
      }
    }
    for(; t+8<=cnt; t+=8){
      uint2 u[8];
      #pragma unroll
      for(int i=0;i<8;i++){
        int s=__builtin_amdgcn_readlane(sv,t+i);
        u[i]=*(const uint2*)(hb+(size_t)s*256+lane4);
      }
      #pragma unroll
      for(int i=0;i<8;i++){
        acc[0]+=rlf(w4[0],t+i)*bflo(u[i].x);
        acc[1]+=rlf(w4[1],t+i)*bfhi(u[i].x);
        acc[2]+=rlf(w4[2],t+i)*bflo(u[i].y);
        acc[3]+=rlf(w4[3],t+i)*bfhi(u[i].y);
      }
    }
    for(; t<cnt; t++){
      int s=__builtin_amdgcn_readlane(sv,t);
      uint2 u=*(const uint2*)(hb+(size_t)s*256+lane4);
      acc[0]+=rlf(w4[0],t)*bflo(u.x);
      acc[1]+=rlf(w4[1],t)*bfhi(u.x);
      acc[2]+=rlf(w4[2],t)*bflo(u.y);
      acc[3]+=rlf(w4[3],t)*bfhi(u.y);
    }
  } else {
    // ---- slow path (deg>64, rare): 3-sweep recompute ----
    #pragma unroll
    for(int k=0;k<4;k++) m[k]=es[k];
    {
      float lm[4]={-1e30f,-1e30f,-1e30f,-1e30f};
      for(int j=o0+lane;j<o1;j+=64){
        int s=ssrc[j];
        float4 avv=*(const float4*)(as_+(size_t)s*4);
        float a[4]={avv.x,avv.y,avv.z,avv.w};
        #pragma unroll
        for(int k=0;k<4;k++) lm[k]=fmaxf(lm[k],lrelu(a[k]+ad[k]));
      }
      #pragma unroll
      for(int k=0;k<4;k++) m[k]=fmaxf(m[k],wred_max(lm[k]));
    }
    {
      float lz[4]={0.f,0.f,0.f,0.f};
      for(int j=o0+lane;j<o1;j+=64){
        int s=ssrc[j];
        float4 avv=*(const float4*)(as_+(size_t)s*4);
        float a[4]={avv.x,avv.y,avv.z,avv.w};
        #pragma unroll
        for(int k=0;k<4;k++) lz[k]+=__expf(lrelu(a[k]+ad[k])-m[k]);
      }
      #pragma unroll
      for(int k=0;k<4;k++){
        float z=wred_sum(lz[k])+__expf(es[k]-m[k]);
        inv[k]=1.f/(z+1e-16f);
      }
    }
    {
      uint2 u=*(const uint2*)(hb+(size_t)n*256+lane4);
      float hv[4]={bflo(u.x),bfhi(u.x),bflo(u.y),bfhi(u.y)};
      #pragma unroll
      for(int k=0;k<4;k++) acc[k]=__expf(es[k]-m[k])*inv[k]*hv[k];
    }
    for(int base=o0;base<o1;base+=64){
      int c2=min(64,o1-base);
      int j=base+lane;
      int sv=0; float w4[4]={0.f,0.f,0.f,0.f};
      if(j<o1){
        sv=ssrc[j];
        float4 avv=*(const float4*)(as_+(size_t)sv*4);
        float a[4]={avv.x,avv.y,avv.z,avv.w};
        #pragma unroll
        for(int k=0;k<4;k++) w4[k]=__expf(lrelu(a[k]+ad[k])-m[k])*inv[k];
      }
      for(int t=0;t<c2;t++){
        int s=__builtin_amdgcn_readlane(sv,t);
        uint2 u=*(const uint2*)(hb+(size_t)s*256+lane4);
        acc[0]+=rlf(w4[0],t)*bflo(u.x);
        acc[1]+=rlf(w4[1],t)*bfhi(u.x);
        acc[2]+=rlf(w4[2],t)*bflo(u.y);
        acc[3]+=rlf(w4[3],t)*bfhi(u.y);
      }
    }
  }
  #pragma unroll
  for(int k=0;k<4;k++) acc[k]+=bias[k*64+lane];
  float tot=wred_sum(acc[0]+acc[1]+acc[2]+acc[3]);
  float mu=tot*(1.f/256.f);
  float vs=0.f;
  #pragma unroll
  for(int k=0;k<4;k++){ float d=acc[k]-mu; vs+=d*d; }
  float var=wred_sum(vs)*(1.f/256.f);
  float r=rsqrtf(var+1e-5f);
  #pragma unroll
  for(int k=0;k<4;k++){
    float v=(acc[k]-mu)*r*g[k*64+lane]+be[k*64+lane];
    float ev= v>0.f? v : expm1f(v);
    outb[(size_t)n*256+k*64+lane]=f2bf(ev);
  }
}

// ---------------- aggregation (heads=1, ch=32, bf16 h) + bias -> d_out ----------------
__global__ __launch_bounds__(256,4) void agg1_k(const ushort* __restrict__ hb,
    const float* __restrict__ as_,const float* __restrict__ ad_,
    const int* __restrict__ offs,const int* __restrict__ ssrc,
    const float* __restrict__ bias,float* __restrict__ out,int N){
  int lane=threadIdx.x&63, wv=threadIdx.x>>6;
  int n=blockIdx.x*4+wv; if(n>=N) return;
  float ad=ad_[n];
  float es=lrelu(as_[n]+ad);
  int o0=offs[n],o1=offs[n+1];
  int cnt=o1-o0;
  float m, inv, acc=0.f;

  if(cnt<=64){
    int sv=0; float lv=-1e30f;
    if(lane<cnt){ sv=ssrc[o0+lane]; lv=lrelu(as_[sv]+ad); }
    m=fmaxf(es,wred_max(lv));
    float w1=(lane<cnt)?__expf(lv-m):0.f;
    float z=wred_sum(w1)+__expf(es-m);
    inv=1.f/(z+1e-16f);
    w1*=inv;
    if(lane<32) acc=__expf(es-m)*inv*__uint_as_float(((unsigned)hb[(size_t)n*32+lane])<<16);
    int t=0;
    for(; t+16<=cnt; t+=16){
      float hv[16];
      #pragma unroll
      for(int i=0;i<16;i++){
        int s=__builtin_amdgcn_readlane(sv,t+i);
        hv[i]=(lane<32)?__uint_as_float(((unsigned)hb[(size_t)s*32+lane])<<16):0.f;
      }
      #pragma unroll
      for(int i=0;i<16;i++) acc+=rlf(w1,t+i)*hv[i];
    }
    for(; t+8<=cnt; t+=8){
      float hv[8];
      #pragma unroll
      for(int i=0;i<8;i++){
        int s=__builtin_amdgcn_readlane(sv,t+i);
        hv[i]=(lane<32)?__uint_as_float(((unsigned)hb[(size_t)s*32+lane])<<16):0.f;
      }
      #pragma unroll
      for(int i=0;i<8;i++) acc+=rlf(w1,t+i)*hv[i];
    }
    for(; t<cnt; t++){
      int s=__builtin_amdgcn_readlane(sv,t);
      if(lane<32) acc+=rlf(w1,t)*__uint_as_float(((unsigned)hb[(size_t)s*32+lane])<<16);
    }
  } else {
    m=es;
    {
      float lm=-1e30f;
      for(int j=o0+lane;j<o1;j+=64) lm=fmaxf(lm,lrelu(as_[ssrc[j]]+ad));
      m=fmaxf(m,wred_max(lm));
    }
    {
      float lz=0.f;
      for(int j=o0+lane;j<o1;j+=64) lz+=__expf(lrelu(as_[ssrc[j]]+ad)-m);
      float z=wred_sum(lz)+__expf(es-m);
      inv=1.f/(z+1e-16f);
    }
    if(lane<32) acc=__expf(es-m)*inv*__uint_as_float(((unsigned)hb[(size_t)n*32+lane])<<16);
    for(int base=o0;base<o1;base+=64){
      int c2=min(64,o1-base);
      int j=base+lane;
      int sv=0; float w1=0.f;
      if(j<o1){ sv=ssrc[j]; w1=__expf(lrelu(as_[sv]+ad)-m)*inv; }
      for(int t=0;t<c2;t++){
        int s=__builtin_amdgcn_readlane(sv,t);
        if(lane<32) acc+=rlf(w1,t)*__uint_as_float(((unsigned)hb[(size_t)s*32+lane])<<16);
      }
    }
  }
  if(lane<32) out[(size_t)n*32+lane]=acc+bias[lane];
}

extern "C" void kernel_launch(void* const* d_in,const int* in_sizes,int n_in,
                              void* d_out,int out_size,void* d_ws,size_t ws_size,
                              hipStream_t stream){
  const float* x  =(const float*)d_in[0];
  const int*   ei =(const int*)  d_in[1];
  const float* W1 =(const float*)d_in[2];
  const float* a1s=(const float*)d_in[3];
  const float* a1d=(const float*)d_in[4];
  const float* b1 =(const float*)d_in[5];
  const float* g1 =(const float*)d_in[6];
  const float* be1=(const float*)d_in[7];
  const float* W2 =(const float*)d_in[8];
  const float* a2s=(const float*)d_in[9];
  const float* a2d=(const float*)d_in[10];
  const float* b2 =(const float*)d_in[11];
  const float* g2 =(const float*)d_in[12];
  const float* be2=(const float*)d_in[13];
  const float* W3 =(const float*)d_in[14];
  const float* a3s=(const float*)d_in[15];
  const float* a3d=(const float*)d_in[16];
  const float* b3 =(const float*)d_in[17];
  float* outp=(float*)d_out;
  int N=NN;
  int E=in_sizes[1]/2;
  const int* srcA=ei;
  const int* dstA=ei+E;

  char* w=(char*)d_ws;
  ushort* hb =(ushort*)w; w+=(size_t)N*256*2;   // bf16 permuted h (layers 1-2)
  ushort* h3b=(ushort*)w; w+=(size_t)N*32*2;    // bf16 h (layer 3)
  ushort* obb=(ushort*)w; w+=(size_t)N*256*2;   // bf16 row-major (next GEMM input)
  ushort* w1t=(ushort*)w; w+=(size_t)256*128*2;
  ushort* w2t=(ushort*)w; w+=(size_t)256*256*2;
  ushort* w3t=(ushort*)w; w+=(size_t)32*256*2;
  float* asb =(float*)w; w+=(size_t)N*4*4;
  float* adb =(float*)w; w+=(size_t)N*4*4;
  int* offs=(int*)w; w+=(size_t)(N+4)*4;
  int* cur =(int*)w; w+=(size_t)N*4;
  int* ssrc=(int*)w; w+=(size_t)E*4;
  int* bsum=(int*)w; w+=(size_t)64*4;

  int NB=(N+1023)/1024;  // 49

  // CSR by dst
  hipMemsetAsync(cur,0,(size_t)N*4,stream);
  hist_k<<<(E+255)/256,256,0,stream>>>(dstA,cur,E);
  scan1_k<<<NB,1024,0,stream>>>(cur,offs,bsum,N);
  scan2_k<<<1,64,0,stream>>>(bsum,NB);
  scan3_k<<<NB,1024,0,stream>>>(offs,bsum,N,E);
  hipMemsetAsync(cur,0,(size_t)N*4,stream);
  scatter_k<<<(E+255)/256,256,0,stream>>>(srcA,dstA,offs,cur,ssrc,E);

  // weight casts
  casttr_k<<<(128*256+255)/256,256,0,stream>>>(W1,w1t,128,256);
  casttr_k<<<(256*256+255)/256,256,0,stream>>>(W2,w2t,256,256);
  casttr_k<<<(256*32+255)/256,256,0,stream>>>(W3,w3t,256,32);

  int nblkN=(N+3)/4;          // 12500
  int gY128=(N+127)/128;      // 391

  // layer 1: x[50000,128](f32) @ W1t[256,128]^T -> bf16 permuted + dots (128x128 tiles)
  gemm_bf16_k<2,2,4,4,1,1><<<dim3(2,gY128),256,0,stream>>>(x,w1t,hb,a1s,a1d,asb,adb,N,256,128);
  agg4_k<<<nblkN,256,0,stream>>>(hb,asb,adb,offs,ssrc,b1,g1,be1,obb,N);

  // layer 2: obb[50000,256] @ W2t[256,256]^T -> bf16 permuted + dots (128x128 tiles)
  gemm_bf16_k<2,2,4,4,1,0><<<dim3(2,gY128),256,0,stream>>>(obb,w2t,hb,a2s,a2d,asb,adb,N,256,256);
  agg4_k<<<nblkN,256,0,stream>>>(hb,asb,adb,offs,ssrc,b2,g2,be2,obb,N);

  // layer 3: obb[50000,256] @ W3t[32,256]^T -> bf16 row-major + dots (heads=1)
  gemm_bf16_k<4,1,2,2,2,0><<<dim3(1,gY128),256,0,stream>>>(obb,w3t,h3b,a3s,a3d,asb,adb,N,32,256);
  agg1_k<<<nblkN,256,0,stream>>>(h3b,asb,adb,offs,ssrc,b3,outp,N);
}

// Round 7
// 360.585 us; speedup vs baseline: 1.0725x; 1.0725x over previous
//
#include <hip/hip_runtime.h>
#include <math.h>

#define NN 50000

typedef __attribute__((ext_vector_type(8))) short bf16x8;
typedef __attribute__((ext_vector_type(4))) float f32x4;

__device__ inline float wred_max(float v){
  #pragma unroll
  for(int s=32;s>0;s>>=1) v=fmaxf(v,__shfl_xor(v,s,64));
  return v;
}
__device__ inline float wred_sum(float v){
  #pragma unroll
  for(int s=32;s>0;s>>=1) v+=__shfl_xor(v,s,64);
  return v;
}
__device__ inline float lrelu(float x){ return x>0.f? x : 0.2f*x; }
__device__ inline float rlf(float v,int l){ return __int_as_float(__builtin_amdgcn_readlane(__float_as_int(v),l)); }

__device__ inline ushort f2bf(float f){
  union{float f;unsigned u;} v; v.f=f;
  unsigned u=v.u;
  return (ushort)((u + 0x7fffu + ((u>>16)&1u)) >> 16);
}
__device__ inline float bflo(unsigned u){ return __uint_as_float(u<<16); }
__device__ inline float bfhi(unsigned u){ return __uint_as_float(u&0xffff0000u); }

// ---------------- casts (weights only) ----------------
__global__ void casttr_k(const float* __restrict__ W, ushort* __restrict__ Wt, int K, int N){
  int i=blockIdx.x*blockDim.x+threadIdx.x;
  if(i<K*N){ int k=i/N, n=i%N; Wt[n*K+k]=f2bf(W[i]); }
}

// ---------------- CSR build ----------------
__global__ void hist_k(const int* __restrict__ dstA,int* __restrict__ counts,int E){
  int i=blockIdx.x*blockDim.x+threadIdx.x;
  if(i<E) atomicAdd(&counts[dstA[i]],1);
}

__global__ __launch_bounds__(1024) void scan1_k(const int* __restrict__ counts,int* __restrict__ offs,
                                                int* __restrict__ bsum,int N){
  __shared__ int stot[16];
  int t=threadIdx.x; int lane=t&63, wv=t>>6;
  int base=blockIdx.x*1024;
  int orig=(base+t<N)?counts[base+t]:0;
  int v=orig;
  #pragma unroll
  for(int s=1;s<64;s<<=1){ int u=__shfl_up(v,s,64); if(lane>=s) v+=u; }
  if(lane==63) stot[wv]=v;
  __syncthreads();
  if(wv==0){
    int tv=(lane<16)?stot[lane]:0;
    #pragma unroll
    for(int s=1;s<16;s<<=1){ int u=__shfl_up(tv,s,64); if(lane>=s) tv+=u; }
    if(lane<16) stot[lane]=tv;
  }
  __syncthreads();
  int wpref=(wv>0)?stot[wv-1]:0;
  if(base+t<N) offs[base+t]=wpref+v-orig;
  if(t==1023) bsum[blockIdx.x]=stot[15];
}
__global__ void scan2_k(int* __restrict__ bsum,int NB){
  int lane=threadIdx.x;
  int v=(lane<NB)?bsum[lane]:0;
  int incl=v;
  #pragma unroll
  for(int s=1;s<64;s<<=1){ int u=__shfl_up(incl,s,64); if(lane>=s) incl+=u; }
  if(lane<NB) bsum[lane]=incl-v;
}
__global__ __launch_bounds__(1024) void scan3_k(int* __restrict__ offs,const int* __restrict__ bsum,int N,int E){
  int i=blockIdx.x*1024+threadIdx.x;
  if(i<N) offs[i]+=bsum[blockIdx.x];
  if(i==N-1) offs[N]=E;
}

__global__ void scatter_k(const int* __restrict__ srcA,const int* __restrict__ dstA,
                          const int* __restrict__ offs,int* cur,int* __restrict__ ssrc,int E){
  int i=blockIdx.x*blockDim.x+threadIdx.x;
  if(i<E){ int d=dstA[i]; int p=offs[d]+atomicAdd(&cur[d],1); ssrc[p]=srcA[i]; }
}

// ---------------- bf16 MFMA GEMM + fused attention dots ----------------
// C = A[M,K] @ Bt[N,K]^T, tile BM x BN, grid (N/BN, M/BM).
// DOTM=1: heads=4, N=256, BN=128 (each wave's 64 cols = one head).
//         Store bf16 head-interleaved perm: chan gc -> 4*(gc&63)+(gc>>6).
// DOTM=2: heads=1, N=32. Store bf16 row-major; dots -> as_[gr], ad_[gr].
template<int WR,int WC,int MI,int NI,int DOTM,int AF32>
__global__ __launch_bounds__(256,2) void gemm_bf16_k(const void* __restrict__ Av,
    const ushort* __restrict__ Bt, ushort* __restrict__ C,
    const float* __restrict__ aS, const float* __restrict__ aD,
    float* __restrict__ as_, float* __restrict__ ad_,
    int M, int N, int K){
  constexpr int BM = WR*MI*16;
  constexpr int BN = WC*NI*16;
  constexpr int LDK = 40;
  __shared__ ushort sA[BM*LDK];
  __shared__ ushort sB[BN*LDK];
  int tid=threadIdx.x;
  int lane=tid&63, w=tid>>6;
  int wr=w/WC, wc=w%WC;
  int bm=blockIdx.y*BM, bn=blockIdx.x*BN;
  f32x4 acc[MI][NI]={};

  for(int k0=0;k0<K;k0+=32){
    if constexpr (AF32){
      const float* A=(const float*)Av;
      #pragma unroll
      for(int i=0;i<(BM*8)/256;i++){
        int c=tid+i*256;
        int r=c>>3, cc=c&7;
        int gr=bm+r;
        float4 v={0.f,0.f,0.f,0.f};
        if(gr<M) v=*(const float4*)(A+(size_t)gr*K+k0+cc*4);
        unsigned long long p=(unsigned long long)f2bf(v.x)
          |((unsigned long long)f2bf(v.y)<<16)
          |((unsigned long long)f2bf(v.z)<<32)
          |((unsigned long long)f2bf(v.w)<<48);
        *(unsigned long long*)(sA+r*LDK+cc*4)=p;
      }
    } else {
      const ushort* A=(const ushort*)Av;
      #pragma unroll
      for(int i=0;i<(BM*4)/256;i++){
        int c=tid+i*256;
        int r=c>>2, cc=c&3;
        int gr=bm+r;
        ulonglong2 v; v.x=0; v.y=0;
        if(gr<M) v=*(const ulonglong2*)(A+(size_t)gr*K+k0+cc*8);
        *(ulonglong2*)(sA+r*LDK+cc*8)=v;
      }
    }
    if constexpr ((BN*4)>=256){
      #pragma unroll
      for(int i=0;i<(BN*4)/256;i++){
        int c=tid+i*256;
        int r=c>>2, cc=c&3;
        ulonglong2 v=*(const ulonglong2*)(Bt+(size_t)(bn+r)*K+k0+cc*8);
        *(ulonglong2*)(sB+r*LDK+cc*8)=v;
      }
    } else {
      if(tid<BN*4){
        int r=tid>>2, cc=tid&3;
        ulonglong2 v=*(const ulonglong2*)(Bt+(size_t)(bn+r)*K+k0+cc*8);
        *(ulonglong2*)(sB+r*LDK+cc*8)=v;
      }
    }
    __syncthreads();
    bf16x8 af[MI], bf[NI];
    #pragma unroll
    for(int m=0;m<MI;m++)
      af[m]=*(bf16x8*)(sA+((wr*MI+m)*16+(lane&15))*LDK+(lane>>4)*8);
    #pragma unroll
    for(int n=0;n<NI;n++)
      bf[n]=*(bf16x8*)(sB+((wc*NI+n)*16+(lane&15))*LDK+(lane>>4)*8);
    #pragma unroll
    for(int m=0;m<MI;m++)
      #pragma unroll
      for(int n=0;n<NI;n++)
        acc[m][n]=__builtin_amdgcn_mfma_f32_16x16x32_bf16(af[m],bf[n],acc[m][n],0,0,0);
    __syncthreads();
  }
  int rb=lane>>4, cl=lane&15;
  float av[NI], dv[NI];
  #pragma unroll
  for(int n=0;n<NI;n++){
    int gc=bn+(wc*NI+n)*16+cl;
    if constexpr (DOTM!=0){ av[n]=aS[gc]; dv[n]=aD[gc]; }
    else { av[n]=0.f; dv[n]=0.f; }
  }
  #pragma unroll
  for(int m=0;m<MI;m++){
    #pragma unroll
    for(int i=0;i<4;i++){
      int gr=bm+(wr*MI+m)*16+rb*4+i;
      if constexpr (DOTM==1){
        int h=(bn>>6)+wc;
        float ps=0.f,pd=0.f;
        #pragma unroll
        for(int n=0;n<NI;n++){ ps+=acc[m][n][i]*av[n]; pd+=acc[m][n][i]*dv[n]; }
        #pragma unroll
        for(int msk=1;msk<16;msk<<=1){
          ps+=__shfl_xor(ps,msk,64); pd+=__shfl_xor(pd,msk,64);
        }
        if(cl==0 && gr<M){ as_[gr*4+h]=ps; ad_[gr*4+h]=pd; }
      } else if constexpr (DOTM==2){
        float ps=0.f,pd=0.f;
        #pragma unroll
        for(int n=0;n<NI;n++){ ps+=acc[m][n][i]*av[n]; pd+=acc[m][n][i]*dv[n]; }
        #pragma unroll
        for(int msk=1;msk<16;msk<<=1){
          ps+=__shfl_xor(ps,msk,64); pd+=__shfl_xor(pd,msk,64);
        }
        if(cl==0 && gr<M){ as_[gr]=ps; ad_[gr]=pd; }
      }
      if(gr<M){
        #pragma unroll
        for(int n=0;n<NI;n++){
          int gc=bn+(wc*NI+n)*16+cl;
          int pos = (DOTM==1) ? (4*(gc&63)+(gc>>6)) : gc;
          C[(size_t)gr*N+pos]=f2bf(acc[m][n][i]);
        }
      }
    }
  }
}

// ---------------- aggregation (heads=4, bf16 permuted h) + bias + LN + ELU ----------------
__global__ __launch_bounds__(256) void agg4_k(const ushort* __restrict__ hb,
    const float* __restrict__ as_,const float* __restrict__ ad_,
    const int* __restrict__ offs,const int* __restrict__ ssrc,
    const float* __restrict__ bias,const float* __restrict__ g,const float* __restrict__ be,
    ushort* __restrict__ outb,int N){
  int lane=threadIdx.x&63, wv=threadIdx.x>>6;
  int n=blockIdx.x*4+wv; if(n>=N) return;
  int lane4=lane*4;
  float ad[4], es[4];
  #pragma unroll
  for(int k=0;k<4;k++) ad[k]=ad_[n*4+k];
  #pragma unroll
  for(int k=0;k<4;k++) es[k]=lrelu(as_[n*4+k]+ad[k]);
  int o0=offs[n],o1=offs[n+1];
  int cnt=o1-o0;
  float m[4], inv[4], acc[4];

  if(cnt<=64){
    // ---- fast path: single gather, logits in registers ----
    int sv=0;
    float lv[4]={-1e30f,-1e30f,-1e30f,-1e30f};
    if(lane<cnt){
      sv=ssrc[o0+lane];
      float4 avv=*(const float4*)(as_+(size_t)sv*4);
      lv[0]=lrelu(avv.x+ad[0]); lv[1]=lrelu(avv.y+ad[1]);
      lv[2]=lrelu(avv.z+ad[2]); lv[3]=lrelu(avv.w+ad[3]);
    }
    #pragma unroll
    for(int k=0;k<4;k++) m[k]=fmaxf(es[k],wred_max(lv[k]));
    float w4[4];
    #pragma unroll
    for(int k=0;k<4;k++) w4[k]=(lane<cnt)?__expf(lv[k]-m[k]):0.f;
    #pragma unroll
    for(int k=0;k<4;k++){
      float z=wred_sum(w4[k])+__expf(es[k]-m[k]);
      inv[k]=1.f/(z+1e-16f);
    }
    #pragma unroll
    for(int k=0;k<4;k++) w4[k]*=inv[k];
    {
      uint2 u=*(const uint2*)(hb+(size_t)n*256+lane4);
      float hv[4]={bflo(u.x),bfhi(u.x),bflo(u.y),bfhi(u.y)};
      #pragma unroll
      for(int k=0;k<4;k++) acc[k]=__expf(es[k]-m[k])*inv[k]*hv[k];
    }
    // double-buffered batches of 8; out-of-range lanes have w4=0, sv=0 (valid addr)
    int cnt8=(cnt+7)&~7;
    uint2 uA[8];
    #pragma unroll
    for(int i=0;i<8;i++){
      int s=__builtin_amdgcn_readlane(sv,i);
      uA[i]=*(const uint2*)(hb+(size_t)s*256+lane4);
    }
    for(int t=0;t<cnt8;t+=8){
      uint2 uB[8];
      if(t+8<cnt8){
        #pragma unroll
        for(int i=0;i<8;i++){
          int s=__builtin_amdgcn_readlane(sv,t+8+i);
          uB[i]=*(const uint2*)(hb+(size_t)s*256+lane4);
        }
      }
      #pragma unroll
      for(int i=0;i<8;i++){
        acc[0]+=rlf(w4[0],t+i)*bflo(uA[i].x);
        acc[1]+=rlf(w4[1],t+i)*bfhi(uA[i].x);
        acc[2]+=rlf(w4[2],t+i)*bflo(uA[i].y);
        acc[3]+=rlf(w4[3],t+i)*bfhi(uA[i].y);
      }
      #pragma unroll
      for(int i=0;i<8;i++) uA[i]=uB[i];
    }
  } else {
    // ---- slow path (deg>64, rare): 3-sweep recompute ----
    #pragma unroll
    for(int k=0;k<4;k++) m[k]=es[k];
    {
      float lm[4]={-1e30f,-1e30f,-1e30f,-1e30f};
      for(int j=o0+lane;j<o1;j+=64){
        int s=ssrc[j];
        float4 avv=*(const float4*)(as_+(size_t)s*4);
        float a[4]={avv.x,avv.y,avv.z,avv.w};
        #pragma unroll
        for(int k=0;k<4;k++) lm[k]=fmaxf(lm[k],lrelu(a[k]+ad[k]));
      }
      #pragma unroll
      for(int k=0;k<4;k++) m[k]=fmaxf(m[k],wred_max(lm[k]));
    }
    {
      float lz[4]={0.f,0.f,0.f,0.f};
      for(int j=o0+lane;j<o1;j+=64){
        int s=ssrc[j];
        float4 avv=*(const float4*)(as_+(size_t)s*4);
        float a[4]={avv.x,avv.y,avv.z,avv.w};
        #pragma unroll
        for(int k=0;k<4;k++) lz[k]+=__expf(lrelu(a[k]+ad[k])-m[k]);
      }
      #pragma unroll
      for(int k=0;k<4;k++){
        float z=wred_sum(lz[k])+__expf(es[k]-m[k]);
        inv[k]=1.f/(z+1e-16f);
      }
    }
    {
      uint2 u=*(const uint2*)(hb+(size_t)n*256+lane4);
      float hv[4]={bflo(u.x),bfhi(u.x),bflo(u.y),bfhi(u.y)};
      #pragma unroll
      for(int k=0;k<4;k++) acc[k]=__expf(es[k]-m[k])*inv[k]*hv[k];
    }
    for(int base=o0;base<o1;base+=64){
      int c2=min(64,o1-base);
      int j=base+lane;
      int sv=0; float w4[4]={0.f,0.f,0.f,0.f};
      if(j<o1){
        sv=ssrc[j];
        float4 avv=*(const float4*)(as_+(size_t)sv*4);
        float a[4]={avv.x,avv.y,avv.z,avv.w};
        #pragma unroll
        for(int k=0;k<4;k++) w4[k]=__expf(lrelu(a[k]+ad[k])-m[k])*inv[k];
      }
      for(int t=0;t<c2;t++){
        int s=__builtin_amdgcn_readlane(sv,t);
        uint2 u=*(const uint2*)(hb+(size_t)s*256+lane4);
        acc[0]+=rlf(w4[0],t)*bflo(u.x);
        acc[1]+=rlf(w4[1],t)*bfhi(u.x);
        acc[2]+=rlf(w4[2],t)*bflo(u.y);
        acc[3]+=rlf(w4[3],t)*bfhi(u.y);
      }
    }
  }
  #pragma unroll
  for(int k=0;k<4;k++) acc[k]+=bias[k*64+lane];
  float tot=wred_sum(acc[0]+acc[1]+acc[2]+acc[3]);
  float mu=tot*(1.f/256.f);
  float vs=0.f;
  #pragma unroll
  for(int k=0;k<4;k++){ float d=acc[k]-mu; vs+=d*d; }
  float var=wred_sum(vs)*(1.f/256.f);
  float r=rsqrtf(var+1e-5f);
  #pragma unroll
  for(int k=0;k<4;k++){
    float v=(acc[k]-mu)*r*g[k*64+lane]+be[k*64+lane];
    float ev= v>0.f? v : expm1f(v);
    outb[(size_t)n*256+k*64+lane]=f2bf(ev);
  }
}

// ---------------- aggregation (heads=1, ch=32, bf16 h) + bias -> d_out ----------------
__global__ __launch_bounds__(256) void agg1_k(const ushort* __restrict__ hb,
    const float* __restrict__ as_,const float* __restrict__ ad_,
    const int* __restrict__ offs,const int* __restrict__ ssrc,
    const float* __restrict__ bias,float* __restrict__ out,int N){
  int lane=threadIdx.x&63, wv=threadIdx.x>>6;
  int n=blockIdx.x*4+wv; if(n>=N) return;
  float ad=ad_[n];
  float es=lrelu(as_[n]+ad);
  int o0=offs[n],o1=offs[n+1];
  int cnt=o1-o0;
  float m, inv, acc=0.f;

  if(cnt<=64){
    int sv=0; float lv=-1e30f;
    if(lane<cnt){ sv=ssrc[o0+lane]; lv=lrelu(as_[sv]+ad); }
    m=fmaxf(es,wred_max(lv));
    float w1=(lane<cnt)?__expf(lv-m):0.f;
    float z=wred_sum(w1)+__expf(es-m);
    inv=1.f/(z+1e-16f);
    w1*=inv;
    if(lane<32) acc=__expf(es-m)*inv*__uint_as_float(((unsigned)hb[(size_t)n*32+lane])<<16);
    int cnt8=(cnt+7)&~7;
    float hA[8];
    #pragma unroll
    for(int i=0;i<8;i++){
      int s=__builtin_amdgcn_readlane(sv,i);
      hA[i]=(lane<32)?__uint_as_float(((unsigned)hb[(size_t)s*32+lane])<<16):0.f;
    }
    for(int t=0;t<cnt8;t+=8){
      float hB[8];
      if(t+8<cnt8){
        #pragma unroll
        for(int i=0;i<8;i++){
          int s=__builtin_amdgcn_readlane(sv,t+8+i);
          hB[i]=(lane<32)?__uint_as_float(((unsigned)hb[(size_t)s*32+lane])<<16):0.f;
        }
      }
      #pragma unroll
      for(int i=0;i<8;i++) acc+=rlf(w1,t+i)*hA[i];
      #pragma unroll
      for(int i=0;i<8;i++) hA[i]=hB[i];
    }
  } else {
    m=es;
    {
      float lm=-1e30f;
      for(int j=o0+lane;j<o1;j+=64) lm=fmaxf(lm,lrelu(as_[ssrc[j]]+ad));
      m=fmaxf(m,wred_max(lm));
    }
    {
      float lz=0.f;
      for(int j=o0+lane;j<o1;j+=64) lz+=__expf(lrelu(as_[ssrc[j]]+ad)-m);
      float z=wred_sum(lz)+__expf(es-m);
      inv=1.f/(z+1e-16f);
    }
    if(lane<32) acc=__expf(es-m)*inv*__uint_as_float(((unsigned)hb[(size_t)n*32+lane])<<16);
    for(int base=o0;base<o1;base+=64){
      int c2=min(64,o1-base);
      int j=base+lane;
      int sv=0; float w1=0.f;
      if(j<o1){ sv=ssrc[j]; w1=__expf(lrelu(as_[sv]+ad)-m)*inv; }
      for(int t=0;t<c2;t++){
        int s=__builtin_amdgcn_readlane(sv,t);
        if(lane<32) acc+=rlf(w1,t)*__uint_as_float(((unsigned)hb[(size_t)s*32+lane])<<16);
      }
    }
  }
  if(lane<32) out[(size_t)n*32+lane]=acc+bias[lane];
}

extern "C" void kernel_launch(void* const* d_in,const int* in_sizes,int n_in,
                              void* d_out,int out_size,void* d_ws,size_t ws_size,
                              hipStream_t stream){
  const float* x  =(const float*)d_in[0];
  const int*   ei =(const int*)  d_in[1];
  const float* W1 =(const float*)d_in[2];
  const float* a1s=(const float*)d_in[3];
  const float* a1d=(const float*)d_in[4];
  const float* b1 =(const float*)d_in[5];
  const float* g1 =(const float*)d_in[6];
  const float* be1=(const float*)d_in[7];
  const float* W2 =(const float*)d_in[8];
  const float* a2s=(const float*)d_in[9];
  const float* a2d=(const float*)d_in[10];
  const float* b2 =(const float*)d_in[11];
  const float* g2 =(const float*)d_in[12];
  const float* be2=(const float*)d_in[13];
  const float* W3 =(const float*)d_in[14];
  const float* a3s=(const float*)d_in[15];
  const float* a3d=(const float*)d_in[16];
  const float* b3 =(const float*)d_in[17];
  float* outp=(float*)d_out;
  int N=NN;
  int E=in_sizes[1]/2;
  const int* srcA=ei;
  const int* dstA=ei+E;

  char* w=(char*)d_ws;
  ushort* hb =(ushort*)w; w+=(size_t)N*256*2;
  ushort* h3b=(ushort*)w; w+=(size_t)N*32*2;
  ushort* obb=(ushort*)w; w+=(size_t)N*256*2;
  ushort* w1t=(ushort*)w; w+=(size_t)256*128*2;
  ushort* w2t=(ushort*)w; w+=(size_t)256*256*2;
  ushort* w3t=(ushort*)w; w+=(size_t)32*256*2;
  float* asb =(float*)w; w+=(size_t)N*4*4;
  float* adb =(float*)w; w+=(size_t)N*4*4;
  int* offs=(int*)w; w+=(size_t)(N+4)*4;
  int* cur =(int*)w; w+=(size_t)N*4;
  int* ssrc=(int*)w; w+=(size_t)E*4;
  int* bsum=(int*)w; w+=(size_t)64*4;

  int NB=(N+1023)/1024;  // 49

  // CSR by dst
  hipMemsetAsync(cur,0,(size_t)N*4,stream);
  hist_k<<<(E+255)/256,256,0,stream>>>(dstA,cur,E);
  scan1_k<<<NB,1024,0,stream>>>(cur,offs,bsum,N);
  scan2_k<<<1,64,0,stream>>>(bsum,NB);
  scan3_k<<<NB,1024,0,stream>>>(offs,bsum,N,E);
  hipMemsetAsync(cur,0,(size_t)N*4,stream);
  scatter_k<<<(E+255)/256,256,0,stream>>>(srcA,dstA,offs,cur,ssrc,E);

  // weight casts
  casttr_k<<<(128*256+255)/256,256,0,stream>>>(W1,w1t,128,256);
  casttr_k<<<(256*256+255)/256,256,0,stream>>>(W2,w2t,256,256);
  casttr_k<<<(256*32+255)/256,256,0,stream>>>(W3,w3t,256,32);

  int nblkN=(N+3)/4;          // 12500
  int gY128=(N+127)/128;      // 391

  // layer 1: x[50000,128](f32) @ W1t[256,128]^T -> bf16 permuted + dots (128x128 tiles)
  gemm_bf16_k<2,2,4,4,1,1><<<dim3(2,gY128),256,0,stream>>>(x,w1t,hb,a1s,a1d,asb,adb,N,256,128);
  agg4_k<<<nblkN,256,0,stream>>>(hb,asb,adb,offs,ssrc,b1,g1,be1,obb,N);

  // layer 2: obb[50000,256] @ W2t[256,256]^T -> bf16 permuted + dots (128x128 tiles)
  gemm_bf16_k<2,2,4,4,1,0><<<dim3(2,gY128),256,0,stream>>>(obb,w2t,hb,a2s,a2d,asb,adb,N,256,256);
  agg4_k<<<nblkN,256,0,stream>>>(hb,asb,adb,offs,ssrc,b2,g2,be2,obb,N);

  // layer 3: obb[50000,256] @ W3t[32,256]^T -> bf16 row-major + dots (heads=1)
  gemm_bf16_k<4,1,2,2,2,0><<<dim3(1,gY128),256,0,stream>>>(obb,w3t,h3b,a3s,a3d,asb,adb,N,32,256);
  agg1_k<<<nblkN,256,0,stream>>>(h3b,asb,adb,offs,ssrc,b3,outp,N);
}

// Round 8
// 344.834 us; speedup vs baseline: 1.1215x; 1.0457x over previous
//
#include <hip/hip_runtime.h>
#include <math.h>

#define NN 50000

typedef __attribute__((ext_vector_type(8))) short bf16x8;
typedef __attribute__((ext_vector_type(4))) float f32x4;

__device__ inline float wred_max(float v){
  #pragma unroll
  for(int s=32;s>0;s>>=1) v=fmaxf(v,__shfl_xor(v,s,64));
  return v;
}
__device__ inline float wred_sum(float v){
  #pragma unroll
  for(int s=32;s>0;s>>=1) v+=__shfl_xor(v,s,64);
  return v;
}
__device__ inline float lrelu(float x){ return x>0.f? x : 0.2f*x; }
__device__ inline float rlf(float v,int l){ return __int_as_float(__builtin_amdgcn_readlane(__float_as_int(v),l)); }

__device__ inline ushort f2bf(float f){
  union{float f;unsigned u;} v; v.f=f;
  unsigned u=v.u;
  return (ushort)((u + 0x7fffu + ((u>>16)&1u)) >> 16);
}
__device__ inline float bflo(unsigned u){ return __uint_as_float(u<<16); }
__device__ inline float bfhi(unsigned u){ return __uint_as_float(u&0xffff0000u); }

// ---------------- casts (weights only) ----------------
__global__ void casttr_k(const float* __restrict__ W, ushort* __restrict__ Wt, int K, int N){
  int i=blockIdx.x*blockDim.x+threadIdx.x;
  if(i<K*N){ int k=i/N, n=i%N; Wt[n*K+k]=f2bf(W[i]); }
}

// ---------------- CSR build ----------------
__global__ void hist_k(const int* __restrict__ dstA,int* __restrict__ counts,int E){
  int i=blockIdx.x*blockDim.x+threadIdx.x;
  if(i<E) atomicAdd(&counts[dstA[i]],1);
}

__global__ __launch_bounds__(1024) void scan1_k(const int* __restrict__ counts,int* __restrict__ offs,
                                                int* __restrict__ bsum,int N){
  __shared__ int stot[16];
  int t=threadIdx.x; int lane=t&63, wv=t>>6;
  int base=blockIdx.x*1024;
  int orig=(base+t<N)?counts[base+t]:0;
  int v=orig;
  #pragma unroll
  for(int s=1;s<64;s<<=1){ int u=__shfl_up(v,s,64); if(lane>=s) v+=u; }
  if(lane==63) stot[wv]=v;
  __syncthreads();
  if(wv==0){
    int tv=(lane<16)?stot[lane]:0;
    #pragma unroll
    for(int s=1;s<16;s<<=1){ int u=__shfl_up(tv,s,64); if(lane>=s) tv+=u; }
    if(lane<16) stot[lane]=tv;
  }
  __syncthreads();
  int wpref=(wv>0)?stot[wv-1]:0;
  if(base+t<N) offs[base+t]=wpref+v-orig;
  if(t==1023) bsum[blockIdx.x]=stot[15];
}
// add exclusive base of block sums (wave 0 computes it) — replaces old scan2+scan3
__global__ __launch_bounds__(1024) void scan3_k(int* __restrict__ offs,const int* __restrict__ bsum,int N,int E){
  __shared__ int sbase;
  int t=threadIdx.x;
  if(t<64){
    int v=(t<(int)blockIdx.x)?bsum[t]:0;
    #pragma unroll
    for(int s=32;s>0;s>>=1) v+=__shfl_xor(v,s,64);
    if(t==0) sbase=v;
  }
  __syncthreads();
  int i=blockIdx.x*1024+t;
  if(i<N) offs[i]+=sbase;
  if(i==N-1) offs[N]=E;
}

__global__ void scatter_k(const int* __restrict__ srcA,const int* __restrict__ dstA,
                          const int* __restrict__ offs,int* cur,int* __restrict__ ssrc,int E){
  int i=blockIdx.x*blockDim.x+threadIdx.x;
  if(i<E){ int d=dstA[i]; int p=offs[d]+atomicAdd(&cur[d],1); ssrc[p]=srcA[i]; }
}

// ---------------- bf16 MFMA GEMM + fused attention dots ----------------
// C = A[M,K] @ Bt[N,K]^T, tile BM x BN, grid (N/BN, M/BM).
// DOTM=1: heads=4, N=256, BN=128 (each wave's 64 cols = one head).
//         Store bf16 head-interleaved perm: chan gc -> 4*(gc&63)+(gc>>6).
// DOTM=2: heads=1, N=32. Store bf16 row-major; dots -> as_[gr], ad_[gr].
template<int WR,int WC,int MI,int NI,int DOTM,int AF32>
__global__ __launch_bounds__(256,2) void gemm_bf16_k(const void* __restrict__ Av,
    const ushort* __restrict__ Bt, ushort* __restrict__ C,
    const float* __restrict__ aS, const float* __restrict__ aD,
    float* __restrict__ as_, float* __restrict__ ad_,
    int M, int N, int K){
  constexpr int BM = WR*MI*16;
  constexpr int BN = WC*NI*16;
  constexpr int LDK = 40;
  __shared__ ushort sA[BM*LDK];
  __shared__ ushort sB[BN*LDK];
  int tid=threadIdx.x;
  int lane=tid&63, w=tid>>6;
  int wr=w/WC, wc=w%WC;
  int bm=blockIdx.y*BM, bn=blockIdx.x*BN;
  f32x4 acc[MI][NI]={};

  for(int k0=0;k0<K;k0+=32){
    if constexpr (AF32){
      const float* A=(const float*)Av;
      #pragma unroll
      for(int i=0;i<(BM*8)/256;i++){
        int c=tid+i*256;
        int r=c>>3, cc=c&7;
        int gr=bm+r;
        float4 v={0.f,0.f,0.f,0.f};
        if(gr<M) v=*(const float4*)(A+(size_t)gr*K+k0+cc*4);
        unsigned long long p=(unsigned long long)f2bf(v.x)
          |((unsigned long long)f2bf(v.y)<<16)
          |((unsigned long long)f2bf(v.z)<<32)
          |((unsigned long long)f2bf(v.w)<<48);
        *(unsigned long long*)(sA+r*LDK+cc*4)=p;
      }
    } else {
      const ushort* A=(const ushort*)Av;
      #pragma unroll
      for(int i=0;i<(BM*4)/256;i++){
        int c=tid+i*256;
        int r=c>>2, cc=c&3;
        int gr=bm+r;
        ulonglong2 v; v.x=0; v.y=0;
        if(gr<M) v=*(const ulonglong2*)(A+(size_t)gr*K+k0+cc*8);
        *(ulonglong2*)(sA+r*LDK+cc*8)=v;
      }
    }
    if constexpr ((BN*4)>=256){
      #pragma unroll
      for(int i=0;i<(BN*4)/256;i++){
        int c=tid+i*256;
        int r=c>>2, cc=c&3;
        ulonglong2 v=*(const ulonglong2*)(Bt+(size_t)(bn+r)*K+k0+cc*8);
        *(ulonglong2*)(sB+r*LDK+cc*8)=v;
      }
    } else {
      if(tid<BN*4){
        int r=tid>>2, cc=tid&3;
        ulonglong2 v=*(const ulonglong2*)(Bt+(size_t)(bn+r)*K+k0+cc*8);
        *(ulonglong2*)(sB+r*LDK+cc*8)=v;
      }
    }
    __syncthreads();
    bf16x8 af[MI], bf[NI];
    #pragma unroll
    for(int m=0;m<MI;m++)
      af[m]=*(bf16x8*)(sA+((wr*MI+m)*16+(lane&15))*LDK+(lane>>4)*8);
    #pragma unroll
    for(int n=0;n<NI;n++)
      bf[n]=*(bf16x8*)(sB+((wc*NI+n)*16+(lane&15))*LDK+(lane>>4)*8);
    #pragma unroll
    for(int m=0;m<MI;m++)
      #pragma unroll
      for(int n=0;n<NI;n++)
        acc[m][n]=__builtin_amdgcn_mfma_f32_16x16x32_bf16(af[m],bf[n],acc[m][n],0,0,0);
    __syncthreads();
  }
  int rb=lane>>4, cl=lane&15;
  float av[NI], dv[NI];
  #pragma unroll
  for(int n=0;n<NI;n++){
    int gc=bn+(wc*NI+n)*16+cl;
    if constexpr (DOTM!=0){ av[n]=aS[gc]; dv[n]=aD[gc]; }
    else { av[n]=0.f; dv[n]=0.f; }
  }
  #pragma unroll
  for(int m=0;m<MI;m++){
    #pragma unroll
    for(int i=0;i<4;i++){
      int gr=bm+(wr*MI+m)*16+rb*4+i;
      if constexpr (DOTM==1){
        int h=(bn>>6)+wc;
        float ps=0.f,pd=0.f;
        #pragma unroll
        for(int n=0;n<NI;n++){ ps+=acc[m][n][i]*av[n]; pd+=acc[m][n][i]*dv[n]; }
        #pragma unroll
        for(int msk=1;msk<16;msk<<=1){
          ps+=__shfl_xor(ps,msk,64); pd+=__shfl_xor(pd,msk,64);
        }
        if(cl==0 && gr<M){ as_[gr*4+h]=ps; ad_[gr*4+h]=pd; }
      } else if constexpr (DOTM==2){
        float ps=0.f,pd=0.f;
        #pragma unroll
        for(int n=0;n<NI;n++){ ps+=acc[m][n][i]*av[n]; pd+=acc[m][n][i]*dv[n]; }
        #pragma unroll
        for(int msk=1;msk<16;msk<<=1){
          ps+=__shfl_xor(ps,msk,64); pd+=__shfl_xor(pd,msk,64);
        }
        if(cl==0 && gr<M){ as_[gr]=ps; ad_[gr]=pd; }
      }
      if(gr<M){
        #pragma unroll
        for(int n=0;n<NI;n++){
          int gc=bn+(wc*NI+n)*16+cl;
          int pos = (DOTM==1) ? (4*(gc&63)+(gc>>6)) : gc;
          C[(size_t)gr*N+pos]=f2bf(acc[m][n][i]);
        }
      }
    }
  }
}

// ---------------- aggregation (heads=4, bf16 permuted h) + bias + LN + ELU ----------------
__global__ __launch_bounds__(256) void agg4_k(const ushort* __restrict__ hb,
    const float* __restrict__ as_,const float* __restrict__ ad_,
    const int* __restrict__ offs,const int* __restrict__ ssrc,
    const float* __restrict__ bias,const float* __restrict__ g,const float* __restrict__ be,
    ushort* __restrict__ outb,int N){
  __shared__ float wlds[4][64][4];   // per-wave edge weights
  int lane=threadIdx.x&63, wv=threadIdx.x>>6;
  int n=blockIdx.x*4+wv; if(n>=N) return;
  int lane4=lane*4;
  float ad[4], es[4];
  #pragma unroll
  for(int k=0;k<4;k++) ad[k]=ad_[n*4+k];
  #pragma unroll
  for(int k=0;k<4;k++) es[k]=lrelu(as_[n*4+k]+ad[k]);
  int o0=offs[n],o1=offs[n+1];
  int cnt=o1-o0;
  float m[4], inv[4], acc[4];

  if(cnt<=64){
    // ---- fast path: single gather; weights -> LDS; static 8-edge batches ----
    int sv=0;
    float lv[4]={-1e30f,-1e30f,-1e30f,-1e30f};
    if(lane<cnt){
      sv=ssrc[o0+lane];
      float4 avv=*(const float4*)(as_+(size_t)sv*4);
      lv[0]=lrelu(avv.x+ad[0]); lv[1]=lrelu(avv.y+ad[1]);
      lv[2]=lrelu(avv.z+ad[2]); lv[3]=lrelu(avv.w+ad[3]);
    }
    #pragma unroll
    for(int k=0;k<4;k++) m[k]=fmaxf(es[k],wred_max(lv[k]));
    float w4[4];
    #pragma unroll
    for(int k=0;k<4;k++) w4[k]=(lane<cnt)?__expf(lv[k]-m[k]):0.f;
    #pragma unroll
    for(int k=0;k<4;k++){
      float z=wred_sum(w4[k])+__expf(es[k]-m[k]);
      inv[k]=1.f/(z+1e-16f);
    }
    #pragma unroll
    for(int k=0;k<4;k++) w4[k]*=inv[k];
    *(float4*)&wlds[wv][lane][0]=make_float4(w4[0],w4[1],w4[2],w4[3]);
    asm volatile("s_waitcnt lgkmcnt(0)":::"memory");
    {
      uint2 u=*(const uint2*)(hb+(size_t)n*256+lane4);
      float hv[4]={bflo(u.x),bfhi(u.x),bflo(u.y),bfhi(u.y)};
      #pragma unroll
      for(int k=0;k<4;k++) acc[k]=__expf(es[k]-m[k])*inv[k]*hv[k];
    }
    // batches of 8; padded slots have w=0, s=0 (valid address)
    int nbat=(cnt+7)>>3;
    for(int b=0;b<nbat;b++){
      int e0=b*8;
      uint2 u[8];
      #pragma unroll
      for(int i=0;i<8;i++){
        int s=__builtin_amdgcn_readlane(sv,e0+i);   // uniform -> SGPR base addressing
        u[i]=*(const uint2*)(hb+((size_t)s<<8)+lane4);
      }
      #pragma unroll
      for(int i=0;i<8;i++){
        const float* wp=&wlds[wv][e0+i][0];          // broadcast ds_read_b128
        acc[0]+=wp[0]*bflo(u[i].x);
        acc[1]+=wp[1]*bfhi(u[i].x);
        acc[2]+=wp[2]*bflo(u[i].y);
        acc[3]+=wp[3]*bfhi(u[i].y);
      }
    }
  } else {
    // ---- slow path (deg>64, rare): 3-sweep recompute ----
    #pragma unroll
    for(int k=0;k<4;k++) m[k]=es[k];
    {
      float lm[4]={-1e30f,-1e30f,-1e30f,-1e30f};
      for(int j=o0+lane;j<o1;j+=64){
        int s=ssrc[j];
        float4 avv=*(const float4*)(as_+(size_t)s*4);
        float a[4]={avv.x,avv.y,avv.z,avv.w};
        #pragma unroll
        for(int k=0;k<4;k++) lm[k]=fmaxf(lm[k],lrelu(a[k]+ad[k]));
      }
      #pragma unroll
      for(int k=0;k<4;k++) m[k]=fmaxf(m[k],wred_max(lm[k]));
    }
    {
      float lz[4]={0.f,0.f,0.f,0.f};
      for(int j=o0+lane;j<o1;j+=64){
        int s=ssrc[j];
        float4 avv=*(const float4*)(as_+(size_t)s*4);
        float a[4]={avv.x,avv.y,avv.z,avv.w};
        #pragma unroll
        for(int k=0;k<4;k++) lz[k]+=__expf(lrelu(a[k]+ad[k])-m[k]);
      }
      #pragma unroll
      for(int k=0;k<4;k++){
        float z=wred_sum(lz[k])+__expf(es[k]-m[k]);
        inv[k]=1.f/(z+1e-16f);
      }
    }
    {
      uint2 u=*(const uint2*)(hb+(size_t)n*256+lane4);
      float hv[4]={bflo(u.x),bfhi(u.x),bflo(u.y),bfhi(u.y)};
      #pragma unroll
      for(int k=0;k<4;k++) acc[k]=__expf(es[k]-m[k])*inv[k]*hv[k];
    }
    for(int base=o0;base<o1;base+=64){
      int c2=min(64,o1-base);
      int j=base+lane;
      int sv=0; float w4[4]={0.f,0.f,0.f,0.f};
      if(j<o1){
        sv=ssrc[j];
        float4 avv=*(const float4*)(as_+(size_t)sv*4);
        float a[4]={avv.x,avv.y,avv.z,avv.w};
        #pragma unroll
        for(int k=0;k<4;k++) w4[k]=__expf(lrelu(a[k]+ad[k])-m[k])*inv[k];
      }
      for(int t=0;t<c2;t++){
        int s=__builtin_amdgcn_readlane(sv,t);
        uint2 u=*(const uint2*)(hb+(size_t)s*256+lane4);
        acc[0]+=rlf(w4[0],t)*bflo(u.x);
        acc[1]+=rlf(w4[1],t)*bfhi(u.x);
        acc[2]+=rlf(w4[2],t)*bflo(u.y);
        acc[3]+=rlf(w4[3],t)*bfhi(u.y);
      }
    }
  }
  #pragma unroll
  for(int k=0;k<4;k++) acc[k]+=bias[k*64+lane];
  float tot=wred_sum(acc[0]+acc[1]+acc[2]+acc[3]);
  float mu=tot*(1.f/256.f);
  float vs=0.f;
  #pragma unroll
  for(int k=0;k<4;k++){ float d=acc[k]-mu; vs+=d*d; }
  float var=wred_sum(vs)*(1.f/256.f);
  float r=rsqrtf(var+1e-5f);
  #pragma unroll
  for(int k=0;k<4;k++){
    float v=(acc[k]-mu)*r*g[k*64+lane]+be[k*64+lane];
    float ev= v>0.f? v : expm1f(v);
    outb[(size_t)n*256+k*64+lane]=f2bf(ev);
  }
}

// ---------------- aggregation (heads=1, ch=32, bf16 h) + bias -> d_out ----------------
__global__ __launch_bounds__(256) void agg1_k(const ushort* __restrict__ hb,
    const float* __restrict__ as_,const float* __restrict__ ad_,
    const int* __restrict__ offs,const int* __restrict__ ssrc,
    const float* __restrict__ bias,float* __restrict__ out,int N){
  int lane=threadIdx.x&63, wv=threadIdx.x>>6;
  int n=blockIdx.x*4+wv; if(n>=N) return;
  float ad=ad_[n];
  float es=lrelu(as_[n]+ad);
  int o0=offs[n],o1=offs[n+1];
  int cnt=o1-o0;
  float m, inv, acc=0.f;
  int lane32=lane&31;
  int half=lane>>5;

  if(cnt<=64){
    int sv=0; float lv=-1e30f;
    if(lane<cnt){ sv=ssrc[o0+lane]; lv=lrelu(as_[sv]+ad); }
    m=fmaxf(es,wred_max(lv));
    float w1=(lane<cnt)?__expf(lv-m):0.f;
    float z=wred_sum(w1)+__expf(es-m);
    inv=1.f/(z+1e-16f);
    w1*=inv;
    // lower half accumulates even edges + self; upper half odd edges
    if(half==0) acc=__expf(es-m)*inv*__uint_as_float(((unsigned)hb[(size_t)n*32+lane32])<<16);
    int cnt2=(cnt+1)&~1;
    for(int t=0;t<cnt2;t+=2){
      int sL=__builtin_amdgcn_readlane(sv,t);
      int sH=__builtin_amdgcn_readlane(sv,t+1);
      float wL=rlf(w1,t), wH=rlf(w1,t+1);
      int s = half? sH : sL;
      float ww = half? wH : wL;
      float hv=__uint_as_float(((unsigned)hb[(size_t)s*32+lane32])<<16);
      acc+=ww*hv;
    }
    acc+=__shfl_xor(acc,32,64);   // merge halves (each lane now has full sum for its channel)
  } else {
    m=es;
    {
      float lm=-1e30f;
      for(int j=o0+lane;j<o1;j+=64) lm=fmaxf(lm,lrelu(as_[ssrc[j]]+ad));
      m=fmaxf(m,wred_max(lm));
    }
    {
      float lz=0.f;
      for(int j=o0+lane;j<o1;j+=64) lz+=__expf(lrelu(as_[ssrc[j]]+ad)-m);
      float z=wred_sum(lz)+__expf(es-m);
      inv=1.f/(z+1e-16f);
    }
    if(lane<32) acc=__expf(es-m)*inv*__uint_as_float(((unsigned)hb[(size_t)n*32+lane])<<16);
    for(int base=o0;base<o1;base+=64){
      int c2=min(64,o1-base);
      int j=base+lane;
      int sv=0; float w1=0.f;
      if(j<o1){ sv=ssrc[j]; w1=__expf(lrelu(as_[sv]+ad)-m)*inv; }
      for(int t=0;t<c2;t++){
        int s=__builtin_amdgcn_readlane(sv,t);
        if(lane<32) acc+=rlf(w1,t)*__uint_as_float(((unsigned)hb[(size_t)s*32+lane])<<16);
      }
    }
  }
  if(lane<32) out[(size_t)n*32+lane]=acc+bias[lane];
}

extern "C" void kernel_launch(void* const* d_in,const int* in_sizes,int n_in,
                              void* d_out,int out_size,void* d_ws,size_t ws_size,
                              hipStream_t stream){
  const float* x  =(const float*)d_in[0];
  const int*   ei =(const int*)  d_in[1];
  const float* W1 =(const float*)d_in[2];
  const float* a1s=(const float*)d_in[3];
  const float* a1d=(const float*)d_in[4];
  const float* b1 =(const float*)d_in[5];
  const float* g1 =(const float*)d_in[6];
  const float* be1=(const float*)d_in[7];
  const float* W2 =(const float*)d_in[8];
  const float* a2s=(const float*)d_in[9];
  const float* a2d=(const float*)d_in[10];
  const float* b2 =(const float*)d_in[11];
  const float* g2 =(const float*)d_in[12];
  const float* be2=(const float*)d_in[13];
  const float* W3 =(const float*)d_in[14];
  const float* a3s=(const float*)d_in[15];
  const float* a3d=(const float*)d_in[16];
  const float* b3 =(const float*)d_in[17];
  float* outp=(float*)d_out;
  int N=NN;
  int E=in_sizes[1]/2;
  const int* srcA=ei;
  const int* dstA=ei+E;

  char* w=(char*)d_ws;
  ushort* hb =(ushort*)w; w+=(size_t)N*256*2;
  ushort* h3b=(ushort*)w; w+=(size_t)N*32*2;
  ushort* obb=(ushort*)w; w+=(size_t)N*256*2;
  ushort* w1t=(ushort*)w; w+=(size_t)256*128*2;
  ushort* w2t=(ushort*)w; w+=(size_t)256*256*2;
  ushort* w3t=(ushort*)w; w+=(size_t)32*256*2;
  float* asb =(float*)w; w+=(size_t)N*4*4;
  float* adb =(float*)w; w+=(size_t)N*4*4;
  int* offs=(int*)w; w+=(size_t)(N+4)*4;
  int* cur =(int*)w; w+=(size_t)N*4;
  int* ssrc=(int*)w; w+=(size_t)E*4;
  int* bsum=(int*)w; w+=(size_t)64*4;

  int NB=(N+1023)/1024;  // 49

  // CSR by dst
  hipMemsetAsync(cur,0,(size_t)N*4,stream);
  hist_k<<<(E+255)/256,256,0,stream>>>(dstA,cur,E);
  scan1_k<<<NB,1024,0,stream>>>(cur,offs,bsum,N);
  scan3_k<<<NB,1024,0,stream>>>(offs,bsum,N,E);
  hipMemsetAsync(cur,0,(size_t)N*4,stream);
  scatter_k<<<(E+255)/256,256,0,stream>>>(srcA,dstA,offs,cur,ssrc,E);

  // weight casts
  casttr_k<<<(128*256+255)/256,256,0,stream>>>(W1,w1t,128,256);
  casttr_k<<<(256*256+255)/256,256,0,stream>>>(W2,w2t,256,256);
  casttr_k<<<(256*32+255)/256,256,0,stream>>>(W3,w3t,256,32);

  int nblkN=(N+3)/4;          // 12500
  int gY128=(N+127)/128;      // 391

  // layer 1: x[50000,128](f32) @ W1t[256,128]^T -> bf16 permuted + dots (128x128 tiles)
  gemm_bf16_k<2,2,4,4,1,1><<<dim3(2,gY128),256,0,stream>>>(x,w1t,hb,a1s,a1d,asb,adb,N,256,128);
  agg4_k<<<nblkN,256,0,stream>>>(hb,asb,adb,offs,ssrc,b1,g1,be1,obb,N);

  // layer 2: obb[50000,256] @ W2t[256,256]^T -> bf16 permuted + dots (128x128 tiles)
  gemm_bf16_k<2,2,4,4,1,0><<<dim3(2,gY128),256,0,stream>>>(obb,w2t,hb,a2s,a2d,asb,adb,N,256,256);
  agg4_k<<<nblkN,256,0,stream>>>(hb,asb,adb,offs,ssrc,b2,g2,be2,obb,N);

  // layer 3: obb[50000,256] @ W3t[32,256]^T -> bf16 row-major + dots (heads=1)
  gemm_bf16_k<4,1,2,2,2,0><<<dim3(1,gY128),256,0,stream>>>(obb,w3t,h3b,a3s,a3d,asb,adb,N,32,256);
  agg1_k<<<nblkN,256,0,stream>>>(h3b,asb,adb,offs,ssrc,b3,outp,N);
}

// Round 9
// 335.720 us; speedup vs baseline: 1.1519x; 1.0271x over previous
//
#include <hip/hip_runtime.h>
#include <math.h>

#define NN 50000

typedef __attribute__((ext_vector_type(8))) short bf16x8;
typedef __attribute__((ext_vector_type(4))) float f32x4;

__device__ inline float wred_max(float v){
  #pragma unroll
  for(int s=32;s>0;s>>=1) v=fmaxf(v,__shfl_xor(v,s,64));
  return v;
}
__device__ inline float wred_sum(float v){
  #pragma unroll
  for(int s=32;s>0;s>>=1) v+=__shfl_xor(v,s,64);
  return v;
}
__device__ inline float lrelu(float x){ return x>0.f? x : 0.2f*x; }
__device__ inline float rlf(float v,int l){ return __int_as_float(__builtin_amdgcn_readlane(__float_as_int(v),l)); }

__device__ inline ushort f2bf(float f){
  union{float f;unsigned u;} v; v.f=f;
  unsigned u=v.u;
  return (ushort)((u + 0x7fffu + ((u>>16)&1u)) >> 16);
}
__device__ inline float bflo(unsigned u){ return __uint_as_float(u<<16); }
__device__ inline float bfhi(unsigned u){ return __uint_as_float(u&0xffff0000u); }

// async global->LDS, 16B per lane; lds dest = wave-uniform base + lane*16
__device__ inline void gload_lds16(const void* g, void* l){
  __builtin_amdgcn_global_load_lds((const __attribute__((address_space(1))) void*)g,
                                   (__attribute__((address_space(3))) void*)l, 16, 0, 0);
}

// ---------------- merged weight casts: W[K,N] f32 -> Wt[N,K] bf16 (x3) ----------------
__global__ void casttr3_k(const float* __restrict__ W1,const float* __restrict__ W2,
                          const float* __restrict__ W3,
                          ushort* __restrict__ w1t,ushort* __restrict__ w2t,ushort* __restrict__ w3t){
  int i=blockIdx.x*256+threadIdx.x;
  if(i<32768){ int k=i>>8, n=i&255; w1t[n*128+k]=f2bf(W1[i]); }
  else if(i<98304){ int j=i-32768; int k=j>>8, n=j&255; w2t[n*256+k]=f2bf(W2[j]); }
  else { int j=i-98304; int k=j>>5, n=j&31; w3t[n*256+k]=f2bf(W3[j]); }
}

// ---------------- CSR build ----------------
__global__ void hist_k(const int* __restrict__ dstA,int* __restrict__ counts,int E){
  int i=blockIdx.x*blockDim.x+threadIdx.x;
  if(i<E) atomicAdd(&counts[dstA[i]],1);
}

// per-block scan + block sums; zeroes counts after reading (replaces 2nd memset)
__global__ __launch_bounds__(1024) void scan1_k(int* __restrict__ counts,int* __restrict__ offs,
                                                int* __restrict__ bsum,int N){
  __shared__ int stot[16];
  int t=threadIdx.x; int lane=t&63, wv=t>>6;
  int base=blockIdx.x*1024;
  int orig=(base+t<N)?counts[base+t]:0;
  int v=orig;
  #pragma unroll
  for(int s=1;s<64;s<<=1){ int u=__shfl_up(v,s,64); if(lane>=s) v+=u; }
  if(lane==63) stot[wv]=v;
  __syncthreads();
  if(wv==0){
    int tv=(lane<16)?stot[lane]:0;
    #pragma unroll
    for(int s=1;s<16;s<<=1){ int u=__shfl_up(tv,s,64); if(lane>=s) tv+=u; }
    if(lane<16) stot[lane]=tv;
  }
  __syncthreads();
  int wpref=(wv>0)?stot[wv-1]:0;
  if(base+t<N){ offs[base+t]=wpref+v-orig; counts[base+t]=0; }
  if(t==1023) bsum[blockIdx.x]=stot[15];
}
// add exclusive base of block sums (wave 0 computes it)
__global__ __launch_bounds__(1024) void scan3_k(int* __restrict__ offs,const int* __restrict__ bsum,int N,int E){
  __shared__ int sbase;
  int t=threadIdx.x;
  if(t<64){
    int v=(t<(int)blockIdx.x)?bsum[t]:0;
    #pragma unroll
    for(int s=32;s>0;s>>=1) v+=__shfl_xor(v,s,64);
    if(t==0) sbase=v;
  }
  __syncthreads();
  int i=blockIdx.x*1024+t;
  if(i<N) offs[i]+=sbase;
  if(i==N-1) offs[N]=E;
}

__global__ void scatter_k(const int* __restrict__ srcA,const int* __restrict__ dstA,
                          const int* __restrict__ offs,int* cur,int* __restrict__ ssrc,int E){
  int i=blockIdx.x*blockDim.x+threadIdx.x;
  if(i<E){ int d=dstA[i]; int p=offs[d]+atomicAdd(&cur[d],1); ssrc[p]=srcA[i]; }
}

// ---------------- bf16 MFMA GEMM + fused attention dots ----------------
// C = A[M,K] @ Bt[N,K]^T, tile BM x BN, grid (N/BN, M/BM).
// LDS: linear 64B rows with XOR chunk swizzle cs = c ^ (r&3); staging via
// global_load_lds (bf16 A, B) with pre-swizzled global source.
// DOTM=1: heads=4, N=256, BN=128. Store bf16 head-interleaved perm: gc -> 4*(gc&63)+(gc>>6).
// DOTM=2: heads=1, N=32. Store bf16 row-major; dots -> as_[gr], ad_[gr].
template<int WR,int WC,int MI,int NI,int DOTM,int AF32>
__global__ __launch_bounds__(256,2) void gemm_bf16_k(const void* __restrict__ Av,
    const ushort* __restrict__ Bt, ushort* __restrict__ C,
    const float* __restrict__ aS, const float* __restrict__ aD,
    float* __restrict__ as_, float* __restrict__ ad_,
    int M, int N, int K){
  constexpr int BM = WR*MI*16;
  constexpr int BN = WC*NI*16;
  __shared__ ushort sA[BM*32];
  __shared__ ushort sB[BN*32];
  int tid=threadIdx.x;
  int lane=tid&63, w=tid>>6;
  int wr=w/WC, wc=w%WC;
  int bm=blockIdx.y*BM, bn=blockIdx.x*BN;
  f32x4 acc[MI][NI]={};

  for(int k0=0;k0<K;k0+=32){
    if constexpr (AF32){
      const float* A=(const float*)Av;
      #pragma unroll
      for(int p=0;p<(BM*4)/256;p++){
        int idx=tid+p*256;
        int r=idx>>2, cs=idx&3;
        int c=cs^(r&3);
        int gr=min(bm+r,M-1);
        float4 v0=*(const float4*)(A+(size_t)gr*K+k0+c*8);
        float4 v1=*(const float4*)(A+(size_t)gr*K+k0+c*8+4);
        ulonglong2 pk;
        pk.x=(unsigned long long)f2bf(v0.x)|((unsigned long long)f2bf(v0.y)<<16)
            |((unsigned long long)f2bf(v0.z)<<32)|((unsigned long long)f2bf(v0.w)<<48);
        pk.y=(unsigned long long)f2bf(v1.x)|((unsigned long long)f2bf(v1.y)<<16)
            |((unsigned long long)f2bf(v1.z)<<32)|((unsigned long long)f2bf(v1.w)<<48);
        *(ulonglong2*)(sA+r*32+cs*8)=pk;
      }
    } else {
      const ushort* A=(const ushort*)Av;
      // 2 async wave-insts per wave: rows w*32+{0,16}, 16 rows each
      #pragma unroll
      for(int rr=0;rr<2;rr++){
        int rbase=w*32+rr*16;
        int r=rbase+(lane>>2);
        int cs=lane&3;
        int c=cs^(r&3);
        int gr=min(bm+r,M-1);
        gload_lds16(A+(size_t)gr*K+k0+c*8, sA+rbase*32);
      }
    }
    {
      // B: BN/16 async wave-insts, round-robin over waves
      #pragma unroll
      for(int i=0;i<(BN/16+3)/4;i++){
        int ii=w+i*4;
        if(ii<BN/16){
          int rbase=ii*16;
          int r=rbase+(lane>>2);
          int cs=lane&3;
          int c=cs^(r&3);
          gload_lds16(Bt+(size_t)(bn+r)*K+k0+c*8, sB+rbase*32);
        }
      }
    }
    __syncthreads();
    bf16x8 af[MI], bf[NI];
    #pragma unroll
    for(int m=0;m<MI;m++){
      int rA=(wr*MI+m)*16+(lane&15);
      af[m]=*(bf16x8*)(sA+rA*32+(((lane>>4)^(rA&3))*8));
    }
    #pragma unroll
    for(int n=0;n<NI;n++){
      int rB=(wc*NI+n)*16+(lane&15);
      bf[n]=*(bf16x8*)(sB+rB*32+(((lane>>4)^(rB&3))*8));
    }
    #pragma unroll
    for(int m=0;m<MI;m++)
      #pragma unroll
      for(int n=0;n<NI;n++)
        acc[m][n]=__builtin_amdgcn_mfma_f32_16x16x32_bf16(af[m],bf[n],acc[m][n],0,0,0);
    __syncthreads();
  }
  int rb=lane>>4, cl=lane&15;
  float av[NI], dv[NI];
  #pragma unroll
  for(int n=0;n<NI;n++){
    int gc=bn+(wc*NI+n)*16+cl;
    if constexpr (DOTM!=0){ av[n]=aS[gc]; dv[n]=aD[gc]; }
    else { av[n]=0.f; dv[n]=0.f; }
  }
  #pragma unroll
  for(int m=0;m<MI;m++){
    #pragma unroll
    for(int i=0;i<4;i++){
      int gr=bm+(wr*MI+m)*16+rb*4+i;
      if constexpr (DOTM==1){
        int h=(bn>>6)+wc;
        float ps=0.f,pd=0.f;
        #pragma unroll
        for(int n=0;n<NI;n++){ ps+=acc[m][n][i]*av[n]; pd+=acc[m][n][i]*dv[n]; }
        #pragma unroll
        for(int msk=1;msk<16;msk<<=1){
          ps+=__shfl_xor(ps,msk,64); pd+=__shfl_xor(pd,msk,64);
        }
        if(cl==0 && gr<M){ as_[gr*4+h]=ps; ad_[gr*4+h]=pd; }
      } else if constexpr (DOTM==2){
        float ps=0.f,pd=0.f;
        #pragma unroll
        for(int n=0;n<NI;n++){ ps+=acc[m][n][i]*av[n]; pd+=acc[m][n][i]*dv[n]; }
        #pragma unroll
        for(int msk=1;msk<16;msk<<=1){
          ps+=__shfl_xor(ps,msk,64); pd+=__shfl_xor(pd,msk,64);
        }
        if(cl==0 && gr<M){ as_[gr]=ps; ad_[gr]=pd; }
      }
      if(gr<M){
        #pragma unroll
        for(int n=0;n<NI;n++){
          int gc=bn+(wc*NI+n)*16+cl;
          int pos = (DOTM==1) ? (4*(gc&63)+(gc>>6)) : gc;
          C[(size_t)gr*N+pos]=f2bf(acc[m][n][i]);
        }
      }
    }
  }
}

// ---------------- aggregation (heads=4, bf16 permuted h) + bias + LN + ELU ----------------
__global__ __launch_bounds__(256) void agg4_k(const ushort* __restrict__ hb,
    const float* __restrict__ as_,const float* __restrict__ ad_,
    const int* __restrict__ offs,const int* __restrict__ ssrc,
    const float* __restrict__ bias,const float* __restrict__ g,const float* __restrict__ be,
    ushort* __restrict__ outb,int N){
  __shared__ float wlds[4][64][4];   // per-wave edge weights
  int lane=threadIdx.x&63, wv=threadIdx.x>>6;
  int n=blockIdx.x*4+wv; if(n>=N) return;
  int lane4=lane*4;
  float ad[4], es[4];
  #pragma unroll
  for(int k=0;k<4;k++) ad[k]=ad_[n*4+k];
  #pragma unroll
  for(int k=0;k<4;k++) es[k]=lrelu(as_[n*4+k]+ad[k]);
  int o0=offs[n],o1=offs[n+1];
  int cnt=o1-o0;
  float m[4], inv[4], acc[4];

  if(cnt<=64){
    // ---- fast path: single gather; weights -> LDS; static 8-edge batches ----
    int sv=0;
    float lv[4]={-1e30f,-1e30f,-1e30f,-1e30f};
    if(lane<cnt){
      sv=ssrc[o0+lane];
      float4 avv=*(const float4*)(as_+(size_t)sv*4);
      lv[0]=lrelu(avv.x+ad[0]); lv[1]=lrelu(avv.y+ad[1]);
      lv[2]=lrelu(avv.z+ad[2]); lv[3]=lrelu(avv.w+ad[3]);
    }
    #pragma unroll
    for(int k=0;k<4;k++) m[k]=fmaxf(es[k],wred_max(lv[k]));
    float w4[4];
    #pragma unroll
    for(int k=0;k<4;k++) w4[k]=(lane<cnt)?__expf(lv[k]-m[k]):0.f;
    #pragma unroll
    for(int k=0;k<4;k++){
      float z=wred_sum(w4[k])+__expf(es[k]-m[k]);
      inv[k]=1.f/(z+1e-16f);
    }
    #pragma unroll
    for(int k=0;k<4;k++) w4[k]*=inv[k];
    *(float4*)&wlds[wv][lane][0]=make_float4(w4[0],w4[1],w4[2],w4[3]);
    asm volatile("s_waitcnt lgkmcnt(0)":::"memory");
    {
      uint2 u=*(const uint2*)(hb+(size_t)n*256+lane4);
      float hv[4]={bflo(u.x),bfhi(u.x),bflo(u.y),bfhi(u.y)};
      #pragma unroll
      for(int k=0;k<4;k++) acc[k]=__expf(es[k]-m[k])*inv[k]*hv[k];
    }
    // batches of 8; padded slots have w=0, s=0 (valid address)
    int nbat=(cnt+7)>>3;
    for(int b=0;b<nbat;b++){
      int e0=b*8;
      uint2 u[8];
      #pragma unroll
      for(int i=0;i<8;i++){
        int s=__builtin_amdgcn_readlane(sv,e0+i);   // uniform -> SGPR base addressing
        u[i]=*(const uint2*)(hb+((size_t)s<<8)+lane4);
      }
      #pragma unroll
      for(int i=0;i<8;i++){
        const float* wp=&wlds[wv][e0+i][0];          // broadcast ds_read_b128
        acc[0]+=wp[0]*bflo(u[i].x);
        acc[1]+=wp[1]*bfhi(u[i].x);
        acc[2]+=wp[2]*bflo(u[i].y);
        acc[3]+=wp[3]*bfhi(u[i].y);
      }
    }
  } else {
    // ---- slow path (deg>64, rare): 3-sweep recompute ----
    #pragma unroll
    for(int k=0;k<4;k++) m[k]=es[k];
    {
      float lm[4]={-1e30f,-1e30f,-1e30f,-1e30f};
      for(int j=o0+lane;j<o1;j+=64){
        int s=ssrc[j];
        float4 avv=*(const float4*)(as_+(size_t)s*4);
        float a[4]={avv.x,avv.y,avv.z,avv.w};
        #pragma unroll
        for(int k=0;k<4;k++) lm[k]=fmaxf(lm[k],lrelu(a[k]+ad[k]));
      }
      #pragma unroll
      for(int k=0;k<4;k++) m[k]=fmaxf(m[k],wred_max(lm[k]));
    }
    {
      float lz[4]={0.f,0.f,0.f,0.f};
      for(int j=o0+lane;j<o1;j+=64){
        int s=ssrc[j];
        float4 avv=*(const float4*)(as_+(size_t)s*4);
        float a[4]={avv.x,avv.y,avv.z,avv.w};
        #pragma unroll
        for(int k=0;k<4;k++) lz[k]+=__expf(lrelu(a[k]+ad[k])-m[k]);
      }
      #pragma unroll
      for(int k=0;k<4;k++){
        float z=wred_sum(lz[k])+__expf(es[k]-m[k]);
        inv[k]=1.f/(z+1e-16f);
      }
    }
    {
      uint2 u=*(const uint2*)(hb+(size_t)n*256+lane4);
      float hv[4]={bflo(u.x),bfhi(u.x),bflo(u.y),bfhi(u.y)};
      #pragma unroll
      for(int k=0;k<4;k++) acc[k]=__expf(es[k]-m[k])*inv[k]*hv[k];
    }
    for(int base=o0;base<o1;base+=64){
      int c2=min(64,o1-base);
      int j=base+lane;
      int sv=0; float w4[4]={0.f,0.f,0.f,0.f};
      if(j<o1){
        sv=ssrc[j];
        float4 avv=*(const float4*)(as_+(size_t)sv*4);
        float a[4]={avv.x,avv.y,avv.z,avv.w};
        #pragma unroll
        for(int k=0;k<4;k++) w4[k]=__expf(lrelu(a[k]+ad[k])-m[k])*inv[k];
      }
      for(int t=0;t<c2;t++){
        int s=__builtin_amdgcn_readlane(sv,t);
        uint2 u=*(const uint2*)(hb+(size_t)s*256+lane4);
        acc[0]+=rlf(w4[0],t)*bflo(u.x);
        acc[1]+=rlf(w4[1],t)*bfhi(u.x);
        acc[2]+=rlf(w4[2],t)*bflo(u.y);
        acc[3]+=rlf(w4[3],t)*bfhi(u.y);
      }
    }
  }
  #pragma unroll
  for(int k=0;k<4;k++) acc[k]+=bias[k*64+lane];
  float tot=wred_sum(acc[0]+acc[1]+acc[2]+acc[3]);
  float mu=tot*(1.f/256.f);
  float vs=0.f;
  #pragma unroll
  for(int k=0;k<4;k++){ float d=acc[k]-mu; vs+=d*d; }
  float var=wred_sum(vs)*(1.f/256.f);
  float r=rsqrtf(var+1e-5f);
  #pragma unroll
  for(int k=0;k<4;k++){
    float v=(acc[k]-mu)*r*g[k*64+lane]+be[k*64+lane];
    float ev= v>0.f? v : expm1f(v);
    outb[(size_t)n*256+k*64+lane]=f2bf(ev);
  }
}

// ---------------- aggregation (heads=1, ch=32, bf16 h) + bias -> d_out ----------------
__global__ __launch_bounds__(256) void agg1_k(const ushort* __restrict__ hb,
    const float* __restrict__ as_,const float* __restrict__ ad_,
    const int* __restrict__ offs,const int* __restrict__ ssrc,
    const float* __restrict__ bias,float* __restrict__ out,int N){
  int lane=threadIdx.x&63, wv=threadIdx.x>>6;
  int n=blockIdx.x*4+wv; if(n>=N) return;
  float ad=ad_[n];
  float es=lrelu(as_[n]+ad);
  int o0=offs[n],o1=offs[n+1];
  int cnt=o1-o0;
  float m, inv, acc=0.f;
  int lane32=lane&31;
  int half=lane>>5;

  if(cnt<=64){
    int sv=0; float lv=-1e30f;
    if(lane<cnt){ sv=ssrc[o0+lane]; lv=lrelu(as_[sv]+ad); }
    m=fmaxf(es,wred_max(lv));
    float w1=(lane<cnt)?__expf(lv-m):0.f;
    float z=wred_sum(w1)+__expf(es-m);
    inv=1.f/(z+1e-16f);
    w1*=inv;
    if(half==0) acc=__expf(es-m)*inv*__uint_as_float(((unsigned)hb[(size_t)n*32+lane32])<<16);
    int cnt2=(cnt+1)&~1;
    for(int t=0;t<cnt2;t+=2){
      int sL=__builtin_amdgcn_readlane(sv,t);
      int sH=__builtin_amdgcn_readlane(sv,t+1);
      float wL=rlf(w1,t), wH=rlf(w1,t+1);
      int s = half? sH : sL;
      float ww = half? wH : wL;
      float hv=__uint_as_float(((unsigned)hb[(size_t)s*32+lane32])<<16);
      acc+=ww*hv;
    }
    acc+=__shfl_xor(acc,32,64);
  } else {
    m=es;
    {
      float lm=-1e30f;
      for(int j=o0+lane;j<o1;j+=64) lm=fmaxf(lm,lrelu(as_[ssrc[j]]+ad));
      m=fmaxf(m,wred_max(lm));
    }
    {
      float lz=0.f;
      for(int j=o0+lane;j<o1;j+=64) lz+=__expf(lrelu(as_[ssrc[j]]+ad)-m);
      float z=wred_sum(lz)+__expf(es-m);
      inv=1.f/(z+1e-16f);
    }
    if(lane<32) acc=__expf(es-m)*inv*__uint_as_float(((unsigned)hb[(size_t)n*32+lane])<<16);
    for(int base=o0;base<o1;base+=64){
      int c2=min(64,o1-base);
      int j=base+lane;
      int sv=0; float w1=0.f;
      if(j<o1){ sv=ssrc[j]; w1=__expf(lrelu(as_[sv]+ad)-m)*inv; }
      for(int t=0;t<c2;t++){
        int s=__builtin_amdgcn_readlane(sv,t);
        if(lane<32) acc+=rlf(w1,t)*__uint_as_float(((unsigned)hb[(size_t)s*32+lane])<<16);
      }
    }
  }
  if(lane<32) out[(size_t)n*32+lane]=acc+bias[lane];
}

extern "C" void kernel_launch(void* const* d_in,const int* in_sizes,int n_in,
                              void* d_out,int out_size,void* d_ws,size_t ws_size,
                              hipStream_t stream){
  const float* x  =(const float*)d_in[0];
  const int*   ei =(const int*)  d_in[1];
  const float* W1 =(const float*)d_in[2];
  const float* a1s=(const float*)d_in[3];
  const float* a1d=(const float*)d_in[4];
  const float* b1 =(const float*)d_in[5];
  const float* g1 =(const float*)d_in[6];
  const float* be1=(const float*)d_in[7];
  const float* W2 =(const float*)d_in[8];
  const float* a2s=(const float*)d_in[9];
  const float* a2d=(const float*)d_in[10];
  const float* b2 =(const float*)d_in[11];
  const float* g2 =(const float*)d_in[12];
  const float* be2=(const float*)d_in[13];
  const float* W3 =(const float*)d_in[14];
  const float* a3s=(const float*)d_in[15];
  const float* a3d=(const float*)d_in[16];
  const float* b3 =(const float*)d_in[17];
  float* outp=(float*)d_out;
  int N=NN;
  int E=in_sizes[1]/2;
  const int* srcA=ei;
  const int* dstA=ei+E;

  char* w=(char*)d_ws;
  ushort* hb =(ushort*)w; w+=(size_t)N*256*2;
  ushort* h3b=(ushort*)w; w+=(size_t)N*32*2;
  ushort* obb=(ushort*)w; w+=(size_t)N*256*2;
  ushort* w1t=(ushort*)w; w+=(size_t)256*128*2;
  ushort* w2t=(ushort*)w; w+=(size_t)256*256*2;
  ushort* w3t=(ushort*)w; w+=(size_t)32*256*2;
  float* asb =(float*)w; w+=(size_t)N*4*4;
  float* adb =(float*)w; w+=(size_t)N*4*4;
  int* offs=(int*)w; w+=(size_t)(N+4)*4;
  int* cur =(int*)w; w+=(size_t)N*4;
  int* ssrc=(int*)w; w+=(size_t)E*4;
  int* bsum=(int*)w; w+=(size_t)64*4;

  int NB=(N+1023)/1024;  // 49

  // CSR by dst (scan1 zeroes cur for scatter's cursor)
  hipMemsetAsync(cur,0,(size_t)N*4,stream);
  hist_k<<<(E+255)/256,256,0,stream>>>(dstA,cur,E);
  scan1_k<<<NB,1024,0,stream>>>(cur,offs,bsum,N);
  scan3_k<<<NB,1024,0,stream>>>(offs,bsum,N,E);
  scatter_k<<<(E+255)/256,256,0,stream>>>(srcA,dstA,offs,cur,ssrc,E);

  // merged weight casts
  casttr3_k<<<416,256,0,stream>>>(W1,W2,W3,w1t,w2t,w3t);

  int nblkN=(N+3)/4;          // 12500
  int gY128=(N+127)/128;      // 391

  // layer 1: x[50000,128](f32) @ W1t[256,128]^T -> bf16 permuted + dots
  gemm_bf16_k<2,2,4,4,1,1><<<dim3(2,gY128),256,0,stream>>>(x,w1t,hb,a1s,a1d,asb,adb,N,256,128);
  agg4_k<<<nblkN,256,0,stream>>>(hb,asb,adb,offs,ssrc,b1,g1,be1,obb,N);

  // layer 2: obb[50000,256] @ W2t[256,256]^T -> bf16 permuted + dots
  gemm_bf16_k<2,2,4,4,1,0><<<dim3(2,gY128),256,0,stream>>>(obb,w2t,hb,a2s,a2d,asb,adb,N,256,256);
  agg4_k<<<nblkN,256,0,stream>>>(hb,asb,adb,offs,ssrc,b2,g2,be2,obb,N);

  // layer 3: obb[50000,256] @ W3t[32,256]^T -> bf16 row-major + dots (heads=1)
  gemm_bf16_k<4,1,2,2,2,0><<<dim3(1,gY128),256,0,stream>>>(obb,w3t,h3b,a3s,a3d,asb,adb,N,32,256);
  agg1_k<<<nblkN,256,0,stream>>>(h3b,asb,adb,offs,ssrc,b3,outp,N);
}

// Round 11
// 327.354 us; speedup vs baseline: 1.1813x; 1.0256x over previous
//
#include <hip/hip_runtime.h>
#include <math.h>

#define NN 50000

typedef __attribute__((ext_vector_type(8))) short bf16x8;
typedef __attribute__((ext_vector_type(4))) float f32x4;

__device__ inline float wred_max(float v){
  #pragma unroll
  for(int s=32;s>0;s>>=1) v=fmaxf(v,__shfl_xor(v,s,64));
  return v;
}
__device__ inline float wred_sum(float v){
  #pragma unroll
  for(int s=32;s>0;s>>=1) v+=__shfl_xor(v,s,64);
  return v;
}
__device__ inline float lrelu(float x){ return x>0.f? x : 0.2f*x; }
__device__ inline float rlf(float v,int l){ return __int_as_float(__builtin_amdgcn_readlane(__float_as_int(v),l)); }

__device__ inline ushort f2bf(float f){
  union{float f;unsigned u;} v; v.f=f;
  unsigned u=v.u;
  return (ushort)((u + 0x7fffu + ((u>>16)&1u)) >> 16);
}
__device__ inline float bflo(unsigned u){ return __uint_as_float(u<<16); }
__device__ inline float bfhi(unsigned u){ return __uint_as_float(u&0xffff0000u); }

// async global->LDS, 16B per lane; lds dest = wave-uniform base + lane*16
__device__ inline void gload_lds16(const void* g, void* l){
  __builtin_amdgcn_global_load_lds((const __attribute__((address_space(1))) void*)g,
                                   (__attribute__((address_space(3))) void*)l, 16, 0, 0);
}

// ---------------- merged weight casts: W[K,N] f32 -> Wt[N,K] bf16 (x3) ----------------
__global__ void casttr3_k(const float* __restrict__ W1,const float* __restrict__ W2,
                          const float* __restrict__ W3,
                          ushort* __restrict__ w1t,ushort* __restrict__ w2t,ushort* __restrict__ w3t){
  int i=blockIdx.x*256+threadIdx.x;
  if(i<32768){ int k=i>>8, n=i&255; w1t[n*128+k]=f2bf(W1[i]); }
  else if(i<98304){ int j=i-32768; int k=j>>8, n=j&255; w2t[n*256+k]=f2bf(W2[j]); }
  else { int j=i-98304; int k=j>>5, n=j&31; w3t[n*256+k]=f2bf(W3[j]); }
}

// ---------------- CSR build ----------------
__global__ void hist_k(const int* __restrict__ dstA,int* __restrict__ counts,int E){
  int i=blockIdx.x*blockDim.x+threadIdx.x;
  if(i<E) atomicAdd(&counts[dstA[i]],1);
}

__global__ __launch_bounds__(1024) void scan1_k(int* __restrict__ counts,int* __restrict__ offs,
                                                int* __restrict__ bsum,int N){
  __shared__ int stot[16];
  int t=threadIdx.x; int lane=t&63, wv=t>>6;
  int base=blockIdx.x*1024;
  int orig=(base+t<N)?counts[base+t]:0;
  int v=orig;
  #pragma unroll
  for(int s=1;s<64;s<<=1){ int u=__shfl_up(v,s,64); if(lane>=s) v+=u; }
  if(lane==63) stot[wv]=v;
  __syncthreads();
  if(wv==0){
    int tv=(lane<16)?stot[lane]:0;
    #pragma unroll
    for(int s=1;s<16;s<<=1){ int u=__shfl_up(tv,s,64); if(lane>=s) tv+=u; }
    if(lane<16) stot[lane]=tv;
  }
  __syncthreads();
  int wpref=(wv>0)?stot[wv-1]:0;
  if(base+t<N){ offs[base+t]=wpref+v-orig; counts[base+t]=0; }
  if(t==1023) bsum[blockIdx.x]=stot[15];
}
__global__ __launch_bounds__(1024) void scan3_k(int* __restrict__ offs,const int* __restrict__ bsum,int N,int E){
  __shared__ int sbase;
  int t=threadIdx.x;
  if(t<64){
    int v=(t<(int)blockIdx.x)?bsum[t]:0;
    #pragma unroll
    for(int s=32;s>0;s>>=1) v+=__shfl_xor(v,s,64);
    if(t==0) sbase=v;
  }
  __syncthreads();
  int i=blockIdx.x*1024+t;
  if(i<N) offs[i]+=sbase;
  if(i==N-1) offs[N]=E;
}

__global__ void scatter_k(const int* __restrict__ srcA,const int* __restrict__ dstA,
                          const int* __restrict__ offs,int* cur,int* __restrict__ ssrc,int E){
  int i=blockIdx.x*blockDim.x+threadIdx.x;
  if(i<E){ int d=dstA[i]; int p=offs[d]+atomicAdd(&cur[d],1); ssrc[p]=srcA[i]; }
}

// ---------------- bf16 MFMA GEMM + fused attention dots ----------------
// C = A[M,K] @ Bt[N,K]^T, tile BM x BN, grid (N/BN, M/BM). C row-major bf16.
// LDS: linear 64B rows, XOR chunk swizzle cs = c ^ (r&3), global_load_lds staging.
// DOTM=1: heads=4, N=256, BN=128 (each wave's 64 cols = one head) -> as_[gr*4+h].
// DOTM=2: heads=1, N=32 -> as_[gr].
template<int WR,int WC,int MI,int NI,int DOTM,int AF32>
__global__ __launch_bounds__(256,2) void gemm_bf16_k(const void* __restrict__ Av,
    const ushort* __restrict__ Bt, ushort* __restrict__ C,
    const float* __restrict__ aS, const float* __restrict__ aD,
    float* __restrict__ as_, float* __restrict__ ad_,
    int M, int N, int K){
  constexpr int BM = WR*MI*16;
  constexpr int BN = WC*NI*16;
  __shared__ ushort sA[BM*32];
  __shared__ ushort sB[BN*32];
  int tid=threadIdx.x;
  int lane=tid&63, w=tid>>6;
  int wr=w/WC, wc=w%WC;
  int bm=blockIdx.y*BM, bn=blockIdx.x*BN;
  f32x4 acc[MI][NI]={};

  for(int k0=0;k0<K;k0+=32){
    if constexpr (AF32){
      const float* A=(const float*)Av;
      #pragma unroll
      for(int p=0;p<(BM*4)/256;p++){
        int idx=tid+p*256;
        int r=idx>>2, cs=idx&3;
        int c=cs^(r&3);
        int gr=min(bm+r,M-1);
        float4 v0=*(const float4*)(A+(size_t)gr*K+k0+c*8);
        float4 v1=*(const float4*)(A+(size_t)gr*K+k0+c*8+4);
        ulonglong2 pk;
        pk.x=(unsigned long long)f2bf(v0.x)|((unsigned long long)f2bf(v0.y)<<16)
            |((unsigned long long)f2bf(v0.z)<<32)|((unsigned long long)f2bf(v0.w)<<48);
        pk.y=(unsigned long long)f2bf(v1.x)|((unsigned long long)f2bf(v1.y)<<16)
            |((unsigned long long)f2bf(v1.z)<<32)|((unsigned long long)f2bf(v1.w)<<48);
        *(ulonglong2*)(sA+r*32+cs*8)=pk;
      }
    } else {
      const ushort* A=(const ushort*)Av;
      #pragma unroll
      for(int rr=0;rr<2;rr++){
        int rbase=w*32+rr*16;
        int r=rbase+(lane>>2);
        int cs=lane&3;
        int c=cs^(r&3);
        int gr=min(bm+r,M-1);
        gload_lds16(A+(size_t)gr*K+k0+c*8, sA+rbase*32);
      }
    }
    {
      #pragma unroll
      for(int i=0;i<(BN/16+3)/4;i++){
        int ii=w+i*4;
        if(ii<BN/16){
          int rbase=ii*16;
          int r=rbase+(lane>>2);
          int cs=lane&3;
          int c=cs^(r&3);
          gload_lds16(Bt+(size_t)(bn+r)*K+k0+c*8, sB+rbase*32);
        }
      }
    }
    __syncthreads();
    bf16x8 af[MI], bf[NI];
    #pragma unroll
    for(int m=0;m<MI;m++){
      int rA=(wr*MI+m)*16+(lane&15);
      af[m]=*(bf16x8*)(sA+rA*32+(((lane>>4)^(rA&3))*8));
    }
    #pragma unroll
    for(int n=0;n<NI;n++){
      int rB=(wc*NI+n)*16+(lane&15);
      bf[n]=*(bf16x8*)(sB+rB*32+(((lane>>4)^(rB&3))*8));
    }
    #pragma unroll
    for(int m=0;m<MI;m++)
      #pragma unroll
      for(int n=0;n<NI;n++)
        acc[m][n]=__builtin_amdgcn_mfma_f32_16x16x32_bf16(af[m],bf[n],acc[m][n],0,0,0);
    __syncthreads();
  }
  int rb=lane>>4, cl=lane&15;
  float av[NI], dv[NI];
  #pragma unroll
  for(int n=0;n<NI;n++){
    int gc=bn+(wc*NI+n)*16+cl;
    if constexpr (DOTM!=0){ av[n]=aS[gc]; dv[n]=aD[gc]; }
    else { av[n]=0.f; dv[n]=0.f; }
  }
  #pragma unroll
  for(int m=0;m<MI;m++){
    #pragma unroll
    for(int i=0;i<4;i++){
      int gr=bm+(wr*MI+m)*16+rb*4+i;
      if constexpr (DOTM==1){
        int h=(bn>>6)+wc;
        float ps=0.f,pd=0.f;
        #pragma unroll
        for(int n=0;n<NI;n++){ ps+=acc[m][n][i]*av[n]; pd+=acc[m][n][i]*dv[n]; }
        #pragma unroll
        for(int msk=1;msk<16;msk<<=1){
          ps+=__shfl_xor(ps,msk,64); pd+=__shfl_xor(pd,msk,64);
        }
        if(cl==0 && gr<M){ as_[gr*4+h]=ps; ad_[gr*4+h]=pd; }
      } else if constexpr (DOTM==2){
        float ps=0.f,pd=0.f;
        #pragma unroll
        for(int n=0;n<NI;n++){ ps+=acc[m][n][i]*av[n]; pd+=acc[m][n][i]*dv[n]; }
        #pragma unroll
        for(int msk=1;msk<16;msk<<=1){
          ps+=__shfl_xor(ps,msk,64); pd+=__shfl_xor(pd,msk,64);
        }
        if(cl==0 && gr<M){ as_[gr]=ps; ad_[gr]=pd; }
      }
      if(gr<M){
        #pragma unroll
        for(int n=0;n<NI;n++){
          int gc=bn+(wc*NI+n)*16+cl;
          C[(size_t)gr*N+gc]=f2bf(acc[m][n][i]);   // row-major, coalesced runs
        }
      }
    }
  }
}

// ---------------- aggregation (heads=4, row-major bf16 h) + bias + LN + ELU ----------------
// lane l owns channels 4l..4l+3, ALL in head h = l>>4.
__global__ __launch_bounds__(256,6) void agg4_k(const ushort* __restrict__ hb,
    const float* __restrict__ as_,const float* __restrict__ ad_,
    const int* __restrict__ offs,const int* __restrict__ ssrc,
    const float* __restrict__ bias,const float* __restrict__ g,const float* __restrict__ be,
    ushort* __restrict__ outb,int N){
  __shared__ float wlds[4][64][4];
  int lane=threadIdx.x&63, wv=threadIdx.x>>6;
  int n=blockIdx.x*4+wv; if(n>=N) return;
  int lane4=lane*4;
  int h=lane>>4;                     // head owning this lane's 4 channels
  float ad[4], es[4];
  #pragma unroll
  for(int k=0;k<4;k++) ad[k]=ad_[n*4+k];
  #pragma unroll
  for(int k=0;k<4;k++) es[k]=lrelu(as_[n*4+k]+ad[k]);
  int o0=offs[n],o1=offs[n+1];
  int cnt=o1-o0;
  float m[4], inv[4], acc[4];

  if(cnt<=64){
    // ---- fast path: single gather; per-head softmax in registers; weights -> LDS ----
    int sv=0;
    float lv[4]={-1e30f,-1e30f,-1e30f,-1e30f};
    if(lane<cnt){
      sv=ssrc[o0+lane];
      float4 avv=*(const float4*)(as_+(size_t)sv*4);
      lv[0]=lrelu(avv.x+ad[0]); lv[1]=lrelu(avv.y+ad[1]);
      lv[2]=lrelu(avv.z+ad[2]); lv[3]=lrelu(avv.w+ad[3]);
    }
    #pragma unroll
    for(int k=0;k<4;k++) m[k]=fmaxf(es[k],wred_max(lv[k]));
    float w4[4];
    #pragma unroll
    for(int k=0;k<4;k++) w4[k]=(lane<cnt)?__expf(lv[k]-m[k]):0.f;
    #pragma unroll
    for(int k=0;k<4;k++){
      float z=wred_sum(w4[k])+__expf(es[k]-m[k]);
      inv[k]=1.f/(z+1e-16f);
    }
    #pragma unroll
    for(int k=0;k<4;k++) w4[k]*=inv[k];
    *(float4*)&wlds[wv][lane][0]=make_float4(w4[0],w4[1],w4[2],w4[3]);
    asm volatile("s_waitcnt lgkmcnt(0)":::"memory");
    { // self-loop: weight of head h applies to all 4 owned channels
      float wself=__expf(es[h]-m[h])*inv[h];
      uint2 u=*(const uint2*)(hb+(size_t)n*256+lane4);
      acc[0]=wself*bflo(u.x); acc[1]=wself*bfhi(u.x);
      acc[2]=wself*bflo(u.y); acc[3]=wself*bfhi(u.y);
    }
    // batches of 16; padded slots: w=0, s=0 (valid address)
    int nbat=(cnt+15)>>4;
    for(int b=0;b<nbat;b++){
      int e0=b*16;
      uint2 u[16];
      #pragma unroll
      for(int i=0;i<16;i++){
        int s=__builtin_amdgcn_readlane(sv,e0+i);   // uniform -> SGPR base
        u[i]=*(const uint2*)(hb+((size_t)s<<8)+lane4);
      }
      #pragma unroll
      for(int i=0;i<16;i++){
        float we=wlds[wv][e0+i][h];                  // broadcast within 16-lane group
        acc[0]+=we*bflo(u[i].x);
        acc[1]+=we*bfhi(u[i].x);
        acc[2]+=we*bflo(u[i].y);
        acc[3]+=we*bfhi(u[i].y);
      }
    }
  } else {
    // ---- slow path (deg>64, rare) ----
    #pragma unroll
    for(int k=0;k<4;k++) m[k]=es[k];
    {
      float lm[4]={-1e30f,-1e30f,-1e30f,-1e30f};
      for(int j=o0+lane;j<o1;j+=64){
        int s=ssrc[j];
        float4 avv=*(const float4*)(as_+(size_t)s*4);
        float a[4]={avv.x,avv.y,avv.z,avv.w};
        #pragma unroll
        for(int k=0;k<4;k++) lm[k]=fmaxf(lm[k],lrelu(a[k]+ad[k]));
      }
      #pragma unroll
      for(int k=0;k<4;k++) m[k]=fmaxf(m[k],wred_max(lm[k]));
    }
    {
      float lz[4]={0.f,0.f,0.f,0.f};
      for(int j=o0+lane;j<o1;j+=64){
        int s=ssrc[j];
        float4 avv=*(const float4*)(as_+(size_t)s*4);
        float a[4]={avv.x,avv.y,avv.z,avv.w};
        #pragma unroll
        for(int k=0;k<4;k++) lz[k]+=__expf(lrelu(a[k]+ad[k])-m[k]);
      }
      #pragma unroll
      for(int k=0;k<4;k++){
        float z=wred_sum(lz[k])+__expf(es[k]-m[k]);
        inv[k]=1.f/(z+1e-16f);
      }
    }
    {
      float wself=__expf(es[h]-m[h])*inv[h];
      uint2 u=*(const uint2*)(hb+(size_t)n*256+lane4);
      acc[0]=wself*bflo(u.x); acc[1]=wself*bfhi(u.x);
      acc[2]=wself*bflo(u.y); acc[3]=wself*bfhi(u.y);
    }
    for(int base=o0;base<o1;base+=64){
      int c2=min(64,o1-base);
      int j=base+lane;
      int sv=0; float w4[4]={0.f,0.f,0.f,0.f};
      if(j<o1){
        sv=ssrc[j];
        float4 avv=*(const float4*)(as_+(size_t)sv*4);
        float a[4]={avv.x,avv.y,avv.z,avv.w};
        #pragma unroll
        for(int k=0;k<4;k++) w4[k]=__expf(lrelu(a[k]+ad[k])-m[k])*inv[k];
      }
      for(int t=0;t<c2;t++){
        int s=__builtin_amdgcn_readlane(sv,t);
        float wa=rlf(w4[0],t),wb=rlf(w4[1],t),wc=rlf(w4[2],t),wd=rlf(w4[3],t);
        float we = h<2 ? (h==0?wa:wb) : (h==2?wc:wd);
        uint2 u=*(const uint2*)(hb+(size_t)s*256+lane4);
        acc[0]+=we*bflo(u.x);
        acc[1]+=we*bfhi(u.x);
        acc[2]+=we*bflo(u.y);
        acc[3]+=we*bfhi(u.y);
      }
    }
  }
  {
    float4 bv=*(const float4*)(bias+lane4);
    acc[0]+=bv.x; acc[1]+=bv.y; acc[2]+=bv.z; acc[3]+=bv.w;
  }
  float tot=wred_sum(acc[0]+acc[1]+acc[2]+acc[3]);
  float mu=tot*(1.f/256.f);
  float vs=0.f;
  #pragma unroll
  for(int k=0;k<4;k++){ float d=acc[k]-mu; vs+=d*d; }
  float var=wred_sum(vs)*(1.f/256.f);
  float r=rsqrtf(var+1e-5f);
  float4 gv=*(const float4*)(g+lane4);
  float4 bev=*(const float4*)(be+lane4);
  float gg[4]={gv.x,gv.y,gv.z,gv.w};
  float bb[4]={bev.x,bev.y,bev.z,bev.w};
  unsigned long long pk=0;
  #pragma unroll
  for(int k=0;k<4;k++){
    float v=(acc[k]-mu)*r*gg[k]+bb[k];
    float ev= v>0.f? v : expm1f(v);
    pk|=((unsigned long long)f2bf(ev))<<(16*k);
  }
  *(unsigned long long*)(outb+(size_t)n*256+lane4)=pk;   // 8B coalesced store
}

// ---------------- aggregation (heads=1, ch=32, bf16 h) + bias -> d_out ----------------
__global__ __launch_bounds__(256) void agg1_k(const ushort* __restrict__ hb,
    const float* __restrict__ as_,const float* __restrict__ ad_,
    const int* __restrict__ offs,const int* __restrict__ ssrc,
    const float* __restrict__ bias,float* __restrict__ out,int N){
  int lane=threadIdx.x&63, wv=threadIdx.x>>6;
  int n=blockIdx.x*4+wv; if(n>=N) return;
  float ad=ad_[n];
  float es=lrelu(as_[n]+ad);
  int o0=offs[n],o1=offs[n+1];
  int cnt=o1-o0;
  float m, inv, acc=0.f;
  int lane32=lane&31;
  int half=lane>>5;

  if(cnt<=64){
    int sv=0; float lv=-1e30f;
    if(lane<cnt){ sv=ssrc[o0+lane]; lv=lrelu(as_[sv]+ad); }
    m=fmaxf(es,wred_max(lv));
    float w1=(lane<cnt)?__expf(lv-m):0.f;
    float z=wred_sum(w1)+__expf(es-m);
    inv=1.f/(z+1e-16f);
    w1*=inv;
    if(half==0) acc=__expf(es-m)*inv*__uint_as_float(((unsigned)hb[(size_t)n*32+lane32])<<16);
    int cnt2=(cnt+1)&~1;
    for(int t=0;t<cnt2;t+=2){
      int sL=__builtin_amdgcn_readlane(sv,t);
      int sH=__builtin_amdgcn_readlane(sv,t+1);
      float wL=rlf(w1,t), wH=rlf(w1,t+1);
      int s = half? sH : sL;
      float ww = half? wH : wL;
      float hv=__uint_as_float(((unsigned)hb[(size_t)s*32+lane32])<<16);
      acc+=ww*hv;
    }
    acc+=__shfl_xor(acc,32,64);
  } else {
    m=es;
    {
      float lm=-1e30f;
      for(int j=o0+lane;j<o1;j+=64) lm=fmaxf(lm,lrelu(as_[ssrc[j]]+ad));
      m=fmaxf(m,wred_max(lm));
    }
    {
      float lz=0.f;
      for(int j=o0+lane;j<o1;j+=64) lz+=__expf(lrelu(as_[ssrc[j]]+ad)-m);
      float z=wred_sum(lz)+__expf(es-m);
      inv=1.f/(z+1e-16f);
    }
    if(lane<32) acc=__expf(es-m)*inv*__uint_as_float(((unsigned)hb[(size_t)n*32+lane])<<16);
    for(int base=o0;base<o1;base+=64){
      int c2=min(64,o1-base);
      int j=base+lane;
      int sv=0; float w1=0.f;
      if(j<o1){ sv=ssrc[j]; w1=__expf(lrelu(as_[sv]+ad)-m)*inv; }
      for(int t=0;t<c2;t++){
        int s=__builtin_amdgcn_readlane(sv,t);
        if(lane<32) acc+=rlf(w1,t)*__uint_as_float(((unsigned)hb[(size_t)s*32+lane])<<16);
      }
    }
  }
  if(lane<32) out[(size_t)n*32+lane]=acc+bias[lane];
}

extern "C" void kernel_launch(void* const* d_in,const int* in_sizes,int n_in,
                              void* d_out,int out_size,void* d_ws,size_t ws_size,
                              hipStream_t stream){
  const float* x  =(const float*)d_in[0];
  const int*   ei =(const int*)  d_in[1];
  const float* W1 =(const float*)d_in[2];
  const float* a1s=(const float*)d_in[3];
  const float* a1d=(const float*)d_in[4];
  const float* b1 =(const float*)d_in[5];
  const float* g1 =(const float*)d_in[6];
  const float* be1=(const float*)d_in[7];
  const float* W2 =(const float*)d_in[8];
  const float* a2s=(const float*)d_in[9];
  const float* a2d=(const float*)d_in[10];
  const float* b2 =(const float*)d_in[11];
  const float* g2 =(const float*)d_in[12];
  const float* be2=(const float*)d_in[13];
  const float* W3 =(const float*)d_in[14];
  const float* a3s=(const float*)d_in[15];
  const float* a3d=(const float*)d_in[16];
  const float* b3 =(const float*)d_in[17];
  float* outp=(float*)d_out;
  int N=NN;
  int E=in_sizes[1]/2;
  const int* srcA=ei;
  const int* dstA=ei+E;

  char* w=(char*)d_ws;
  ushort* hb =(ushort*)w; w+=(size_t)N*256*2;
  ushort* h3b=(ushort*)w; w+=(size_t)N*32*2;
  ushort* obb=(ushort*)w; w+=(size_t)N*256*2;
  ushort* w1t=(ushort*)w; w+=(size_t)256*128*2;
  ushort* w2t=(ushort*)w; w+=(size_t)256*256*2;
  ushort* w3t=(ushort*)w; w+=(size_t)32*256*2;
  float* asb =(float*)w; w+=(size_t)N*4*4;
  float* adb =(float*)w; w+=(size_t)N*4*4;
  int* offs=(int*)w; w+=(size_t)(N+4)*4;
  int* cur =(int*)w; w+=(size_t)N*4;
  int* ssrc=(int*)w; w+=(size_t)E*4;
  int* bsum=(int*)w; w+=(size_t)64*4;

  int NB=(N+1023)/1024;  // 49

  // CSR by dst (scan1 zeroes cur for scatter's cursor)
  hipMemsetAsync(cur,0,(size_t)N*4,stream);
  hist_k<<<(E+255)/256,256,0,stream>>>(dstA,cur,E);
  scan1_k<<<NB,1024,0,stream>>>(cur,offs,bsum,N);
  scan3_k<<<NB,1024,0,stream>>>(offs,bsum,N,E);
  scatter_k<<<(E+255)/256,256,0,stream>>>(srcA,dstA,offs,cur,ssrc,E);

  // merged weight casts
  casttr3_k<<<416,256,0,stream>>>(W1,W2,W3,w1t,w2t,w3t);

  int nblkN=(N+3)/4;          // 12500
  int gY128=(N+127)/128;      // 391

  // layer 1: x[50000,128](f32) @ W1t[256,128]^T -> bf16 row-major + dots
  gemm_bf16_k<2,2,4,4,1,1><<<dim3(2,gY128),256,0,stream>>>(x,w1t,hb,a1s,a1d,asb,adb,N,256,128);
  agg4_k<<<nblkN,256,0,stream>>>(hb,asb,adb,offs,ssrc,b1,g1,be1,obb,N);

  // layer 2: obb[50000,256] @ W2t[256,256]^T -> bf16 row-major + dots
  gemm_bf16_k<2,2,4,4,1,0><<<dim3(2,gY128),256,0,stream>>>(obb,w2t,hb,a2s,a2d,asb,adb,N,256,256);
  agg4_k<<<nblkN,256,0,stream>>>(hb,asb,adb,offs,ssrc,b2,g2,be2,obb,N);

  // layer 3: obb[50000,256] @ W3t[32,256]^T -> bf16 row-major + dots (heads=1)
  gemm_bf16_k<4,1,2,2,2,0><<<dim3(1,gY128),256,0,stream>>>(obb,w3t,h3b,a3s,a3d,asb,adb,N,32,256);
  agg1_k<<<nblkN,256,0,stream>>>(h3b,asb,adb,offs,ssrc,b3,outp,N);
}